// Round 4
// baseline (4283.484 us; speedup 1.0000x reference)
//
#include <hip/hip_runtime.h>
#include <cstdint>
#include <cstddef>

// Problem constants
constexpr int Bc   = 2;
constexpr int Sc   = 2048;
constexpr int Dm   = 768;
constexpr int Hc   = 12;
constexpr int HD   = 64;
constexpr int DI   = 1536;
constexpr int NST  = 16;
constexpr int DTR  = 48;
constexpr int CAP  = 256;   // 0.125 * S
constexpr int DF   = 3072;
constexpr int M_   = Bc * Sc;  // 4096 tokens
constexpr int NQ   = Bc * Hc * Sc;  // 49152 (b,h,s) query rows
constexpr int NCH  = 4;             // key chunks

// ---------------------------------------------------------------------------
// Activation codes: 0 none, 1 softplus, 2 sigmoid, 3 relu, 4 gelu(exact)
__device__ __forceinline__ float apply_act(float v, int act) {
    switch (act) {
        case 1: return (v > 20.f) ? v : log1pf(__expf(v));
        case 2: return 1.f / (1.f + __expf(-v));
        case 3: return fmaxf(v, 0.f);
        case 4: return 0.5f * v * (1.f + erff(v * 0.70710678118654752f));
        default: return v;
    }
}

// ---------------------------------------------------------------------------
// Generic fp32 GEMM: C[M,N] = act(acc*C + A[M,K](lda) @ W[K,N] + bias)
// __launch_bounds__(256,4): min 4 waves/EU -> VGPR cap 128. The 8x8 microtile
// needs ~92 VGPRs; the default heuristic capped at 68 and SPILLED the
// accumulators to scratch (round-3 profile: VGPR_Count=68, VALUBusy 3.8%).
__global__ __launch_bounds__(256, 4) void gemm_kernel(
    const float* __restrict__ A, int lda,
    const float* __restrict__ W,
    const float* __restrict__ bias,
    float* __restrict__ C,
    int M, int N, int K, int act, int accflag)
{
    __shared__ float As[16][132];
    __shared__ float Bs[16][132];
    const int tid = threadIdx.x;
    const int bm = blockIdx.y * 128;
    const int bn = blockIdx.x * 128;
    const int tx = tid & 15, ty = tid >> 4;

    float acc[8][8];
#pragma unroll
    for (int i = 0; i < 8; ++i)
#pragma unroll
        for (int j = 0; j < 8; ++j) acc[i][j] = 0.f;

    for (int k0 = 0; k0 < K; k0 += 16) {
#pragma unroll
        for (int i = 0; i < 2; ++i) {
            int f = tid + 256 * i;
            int row = f >> 2;
            int kc = (f & 3) * 4;
            const float* ap = A + (size_t)(bm + row) * lda + (k0 + kc);
            float4 v = *(const float4*)ap;
            As[kc + 0][row] = v.x; As[kc + 1][row] = v.y;
            As[kc + 2][row] = v.z; As[kc + 3][row] = v.w;
        }
#pragma unroll
        for (int i = 0; i < 2; ++i) {
            int f = tid + 256 * i;
            int row = f >> 5;
            int col = (f & 31) * 4;
            int gn = bn + col;
            const float* wp = W + (size_t)(k0 + row) * N + gn;
            float4 v;
            if (gn + 3 < N) v = *(const float4*)wp;
            else {
                v.x = (gn + 0 < N) ? wp[0] : 0.f;
                v.y = (gn + 1 < N) ? wp[1] : 0.f;
                v.z = (gn + 2 < N) ? wp[2] : 0.f;
                v.w = (gn + 3 < N) ? wp[3] : 0.f;
            }
            *(float4*)&Bs[row][col] = v;
        }
        __syncthreads();
#pragma unroll
        for (int kk = 0; kk < 16; ++kk) {
            float a[8], b[8];
            *(float4*)&a[0] = *(const float4*)&As[kk][ty * 4];
            *(float4*)&a[4] = *(const float4*)&As[kk][64 + ty * 4];
            *(float4*)&b[0] = *(const float4*)&Bs[kk][tx * 4];
            *(float4*)&b[4] = *(const float4*)&Bs[kk][64 + tx * 4];
#pragma unroll
            for (int i = 0; i < 8; ++i)
#pragma unroll
                for (int j = 0; j < 8; ++j)
                    acc[i][j] = fmaf(a[i], b[j], acc[i][j]);
        }
        __syncthreads();
    }

#pragma unroll
    for (int ii = 0; ii < 8; ++ii) {
        int row = bm + ((ii < 4) ? (ty * 4 + ii) : (64 + ty * 4 + ii - 4));
#pragma unroll
        for (int jj = 0; jj < 8; ++jj) {
            int col = bn + ((jj < 4) ? (tx * 4 + jj) : (64 + tx * 4 + jj - 4));
            if (col < N) {
                size_t cidx = (size_t)row * N + col;
                float v = acc[ii][jj];
                if (accflag) v += C[cidx];
                if (bias) v += bias[col];
                C[cidx] = apply_act(v, act);
            }
        }
    }
}

// ---------------------------------------------------------------------------
__global__ __launch_bounds__(256) void ln_kernel(
    const float* __restrict__ x, const float* __restrict__ w,
    const float* __restrict__ b, float* __restrict__ out)
{
    const int row = blockIdx.x, tid = threadIdx.x;
    const float* xp = x + (size_t)row * Dm;
    float v0 = xp[tid], v1 = xp[tid + 256], v2 = xp[tid + 512];
    float s1 = v0 + v1 + v2;
    float s2 = v0 * v0 + v1 * v1 + v2 * v2;
#pragma unroll
    for (int off = 32; off; off >>= 1) {
        s1 += __shfl_down(s1, off, 64);
        s2 += __shfl_down(s2, off, 64);
    }
    __shared__ float r1[4], r2[4];
    int wid = tid >> 6, lane = tid & 63;
    if (lane == 0) { r1[wid] = s1; r2[wid] = s2; }
    __syncthreads();
    s1 = r1[0] + r1[1] + r1[2] + r1[3];
    s2 = r2[0] + r2[1] + r2[2] + r2[3];
    float mu = s1 * (1.f / 768.f);
    float var = s2 * (1.f / 768.f) - mu * mu;
    float rstd = rsqrtf(var + 1e-5f);
    float* op = out + (size_t)row * Dm;
    op[tid]       = (v0 - mu) * rstd * w[tid]       + b[tid];
    op[tid + 256] = (v1 - mu) * rstd * w[tid + 256] + b[tid + 256];
    op[tid + 512] = (v2 - mu) * rstd * w[tid + 512] + b[tid + 512];
}

// ---------------------------------------------------------------------------
__global__ __launch_bounds__(256) void rope_kernel(float* __restrict__ qkv)
{
    int id = blockIdx.x * 256 + threadIdx.x;   // B*S*H*32
    int i = id & 31;
    int h = (id >> 5) % Hc;
    int r = id / (32 * Hc);        // b*S + s
    int s = r & (Sc - 1);
    float inv = powf(10000.f, -(float)(2 * i) * (1.f / 64.f));
    float f = (float)s * inv;
    float sn, cs;
    sincosf(f, &sn, &cs);
    float* base = qkv + (size_t)r * 2304 + h * 64 + i;
    float q1 = base[0], q2 = base[32];
    base[0]  = q1 * cs - q2 * sn;
    base[32] = q1 * sn + q2 * cs;
    float* kb = base + Dm;
    float k1 = kb[0], k2 = kb[32];
    kb[0]  = k1 * cs - k2 * sn;
    kb[32] = k1 * sn + k2 * cs;
}

// ---------------------------------------------------------------------------
// Flash-attention partial over a 512-key chunk.
// Block: 256 threads = 128 lane-pairs; pair p handles queries (2p, 2p+1);
// lane u=tid&1 holds dims [32u, 32u+32). Full dots via shfl_xor(.,1).
// Writes unnormalized o plus (m,l) per (chunk, query).
__global__ __launch_bounds__(256) void attn_partial_kernel(
    const float* __restrict__ qkv, float* __restrict__ po,
    float* __restrict__ pm, float* __restrict__ pl)
{
    __shared__ float Kt[64][64];
    __shared__ float Vt[64][64];
    const int tid = threadIdx.x;
    const int bh = blockIdx.y;              // 0..23
    const int b = bh / Hc, h = bh % Hc;
    const int chunk = blockIdx.z;           // 0..3
    const int u = tid & 1;
    const int pr = tid >> 1;                // 0..127
    const int sA = blockIdx.x * 256 + 2 * pr;

    float qA[32], qB[32], oA[32], oB[32];
    {
        const float* qpA = qkv + ((size_t)(b * Sc + sA)) * 2304 + h * 64 + 32 * u;
        const float* qpB = qpA + 2304;
#pragma unroll
        for (int i = 0; i < 8; ++i) {
            float4 a = *(const float4*)(qpA + 4 * i);
            float4 bb = *(const float4*)(qpB + 4 * i);
            qA[4*i+0] = a.x * 0.125f; qA[4*i+1] = a.y * 0.125f;
            qA[4*i+2] = a.z * 0.125f; qA[4*i+3] = a.w * 0.125f;
            qB[4*i+0] = bb.x * 0.125f; qB[4*i+1] = bb.y * 0.125f;
            qB[4*i+2] = bb.z * 0.125f; qB[4*i+3] = bb.w * 0.125f;
        }
    }
#pragma unroll
    for (int i = 0; i < 32; ++i) { oA[i] = 0.f; oB[i] = 0.f; }
    float mA = -1e30f, lA = 0.f, mB = -1e30f, lB = 0.f;

    const int k0base = chunk * 512;
    for (int kt = 0; kt < 512; kt += 64) {
        // stage 64 keys x 64 dims of K and V
#pragma unroll
        for (int i = 0; i < 8; ++i) {
            int f = tid + 256 * i;          // 0..2047
            int isV = f >> 10;              // 0:K 1:V
            int g = f & 1023;
            int row = g >> 4;
            int c4 = (g & 15) * 4;
            const float* src = qkv + ((size_t)(b * Sc + k0base + kt + row)) * 2304
                             + Dm + isV * Dm + h * 64 + c4;
            if (isV) *(float4*)&Vt[row][c4] = *(const float4*)src;
            else     *(float4*)&Kt[row][c4] = *(const float4*)src;
        }
        __syncthreads();

#pragma unroll 1
        for (int j0 = 0; j0 < 64; j0 += 8) {
            float pa[8], pb[8];
#pragma unroll
            for (int jj = 0; jj < 8; ++jj) {
                const float* kr = &Kt[j0 + jj][32 * u];
                float da0 = 0.f, da1 = 0.f, db0 = 0.f, db1 = 0.f;
#pragma unroll
                for (int c = 0; c < 4; ++c) {
                    float4 k1v = *(const float4*)(kr + 8 * c);
                    float4 k2v = *(const float4*)(kr + 8 * c + 4);
                    da0 += qA[8*c+0]*k1v.x + qA[8*c+1]*k1v.y + qA[8*c+2]*k1v.z + qA[8*c+3]*k1v.w;
                    da1 += qA[8*c+4]*k2v.x + qA[8*c+5]*k2v.y + qA[8*c+6]*k2v.z + qA[8*c+7]*k2v.w;
                    db0 += qB[8*c+0]*k1v.x + qB[8*c+1]*k1v.y + qB[8*c+2]*k1v.z + qB[8*c+3]*k1v.w;
                    db1 += qB[8*c+4]*k2v.x + qB[8*c+5]*k2v.y + qB[8*c+6]*k2v.z + qB[8*c+7]*k2v.w;
                }
                float da = da0 + da1;
                float db = db0 + db1;
                da += __shfl_xor(da, 1, 64);
                db += __shfl_xor(db, 1, 64);
                pa[jj] = da; pb[jj] = db;
            }
            // branchless online-softmax rescale, amortized over 8 keys
            float cmA = pa[0], cmB = pb[0];
#pragma unroll
            for (int jj = 1; jj < 8; ++jj) {
                cmA = fmaxf(cmA, pa[jj]); cmB = fmaxf(cmB, pb[jj]);
            }
            float nmA = fmaxf(mA, cmA), nmB = fmaxf(mB, cmB);
            float sfA = __expf(mA - nmA), sfB = __expf(mB - nmB);
            mA = nmA; mB = nmB;
            lA *= sfA; lB *= sfB;
#pragma unroll
            for (int i = 0; i < 32; ++i) { oA[i] *= sfA; oB[i] *= sfB; }
#pragma unroll
            for (int jj = 0; jj < 8; ++jj) {
                pa[jj] = __expf(pa[jj] - mA); lA += pa[jj];
                pb[jj] = __expf(pb[jj] - mB); lB += pb[jj];
            }
#pragma unroll
            for (int jj = 0; jj < 8; ++jj) {
                const float* vr = &Vt[j0 + jj][32 * u];
                float paj = pa[jj], pbj = pb[jj];
#pragma unroll
                for (int c = 0; c < 8; ++c) {
                    float4 vv = *(const float4*)(vr + 4 * c);
                    oA[4*c+0] += paj * vv.x; oA[4*c+1] += paj * vv.y;
                    oA[4*c+2] += paj * vv.z; oA[4*c+3] += paj * vv.w;
                    oB[4*c+0] += pbj * vv.x; oB[4*c+1] += pbj * vv.y;
                    oB[4*c+2] += pbj * vv.z; oB[4*c+3] += pbj * vv.w;
                }
            }
        }
        __syncthreads();
    }

    const size_t qiA = (size_t)bh * Sc + sA;
    const size_t qiB = qiA + 1;
    float* poA = po + ((size_t)chunk * NQ + qiA) * 64 + 32 * u;
    float* poB = po + ((size_t)chunk * NQ + qiB) * 64 + 32 * u;
#pragma unroll
    for (int i = 0; i < 8; ++i) {
        float4 t;
        t.x = oA[4*i+0]; t.y = oA[4*i+1]; t.z = oA[4*i+2]; t.w = oA[4*i+3];
        *(float4*)(poA + 4 * i) = t;
        t.x = oB[4*i+0]; t.y = oB[4*i+1]; t.z = oB[4*i+2]; t.w = oB[4*i+3];
        *(float4*)(poB + 4 * i) = t;
    }
    if (u == 0) {
        pm[(size_t)chunk * NQ + qiA] = mA;
        pl[(size_t)chunk * NQ + qiA] = lA;
        pm[(size_t)chunk * NQ + qiB] = mB;
        pl[(size_t)chunk * NQ + qiB] = lB;
    }
}

// Merge NCH partials -> ao (B,S,Dm). Block = 4 queries x 64 dims.
__global__ __launch_bounds__(256) void attn_combine_kernel(
    const float* __restrict__ po, const float* __restrict__ pm,
    const float* __restrict__ pl, float* __restrict__ ao)
{
    const int tid = threadIdx.x;
    const int d = tid & 63;
    const int qi = blockIdx.x * 4 + (tid >> 6);   // bh*Sc + s
    const int bh = qi >> 11;
    const int s = qi & (Sc - 1);
    const int b = bh / Hc, h = bh % Hc;
    float m0 = pm[qi], m1 = pm[NQ + qi], m2 = pm[2*NQ + qi], m3 = pm[3*NQ + qi];
    float M = fmaxf(fmaxf(m0, m1), fmaxf(m2, m3));
    float w0 = __expf(m0 - M), w1 = __expf(m1 - M);
    float w2 = __expf(m2 - M), w3 = __expf(m3 - M);
    float l = w0 * pl[qi] + w1 * pl[NQ + qi] + w2 * pl[2*NQ + qi] + w3 * pl[3*NQ + qi];
    float o = w0 * po[(size_t)qi * 64 + d]
            + w1 * po[((size_t)NQ + qi) * 64 + d]
            + w2 * po[((size_t)2*NQ + qi) * 64 + d]
            + w3 * po[((size_t)3*NQ + qi) * 64 + d];
    ao[((size_t)(b * Sc + s)) * Dm + h * 64 + d] = o / l;
}

// ---------------------------------------------------------------------------
__global__ __launch_bounds__(256) void conv_silu_kernel(
    const float* __restrict__ xz, const float* __restrict__ cw,
    const float* __restrict__ cb, float* __restrict__ u)
{
    int id = blockIdx.x * 256 + threadIdx.x;   // B*S*DI
    int d = id % DI;
    int r = id / DI;
    int s = r & (Sc - 1);
    int b = r >> 11;
    float acc = cb[d];
#pragma unroll
    for (int j = 0; j < 4; ++j) {
        int sp = s + j - 3;
        if (sp >= 0)
            acc += xz[((size_t)(b * Sc + sp)) * (2 * DI) + d] * cw[d * 4 + j];
    }
    u[id] = acc / (1.f + __expf(-acc));
}

// ---------------------------------------------------------------------------
__global__ __launch_bounds__(256) void scan_kernel(
    const float* __restrict__ delta, const float* __restrict__ u,
    const float* __restrict__ dbc, const float* __restrict__ A_log,
    const float* __restrict__ Dp, float* __restrict__ y)
{
    int gid = blockIdx.x * 256 + threadIdx.x;
    int n = gid & 15;
    int ch = gid >> 4;
    int b = ch / DI;
    int dd = ch - b * DI;
    float Av = -__expf(A_log[dd * NST + n]);
    float Dv = Dp[dd];
    const float* dp = delta + (size_t)b * Sc * DI + dd;
    const float* up = u     + (size_t)b * Sc * DI + dd;
    const float* Bp = dbc   + (size_t)b * Sc * 80 + DTR + n;
    const float* Cp = Bp + NST;
    float* yp = y + (size_t)b * Sc * DI + dd;

    float h = 0.f;
    constexpr int CH = 8;
    float cdt[CH], cu[CH], cB[CH], cC[CH];
    float ndt[CH], nu[CH], nB[CH], nC[CH];
#pragma unroll
    for (int i = 0; i < CH; ++i) {
        cdt[i] = dp[(size_t)i * DI]; cu[i] = up[(size_t)i * DI];
        cB[i] = Bp[(size_t)i * 80];  cC[i] = Cp[(size_t)i * 80];
    }
    for (int t0 = 0; t0 < Sc; t0 += CH) {
        bool more = (t0 + CH < Sc);
        if (more) {
#pragma unroll
            for (int i = 0; i < CH; ++i) {
                size_t t = t0 + CH + i;
                ndt[i] = dp[t * DI]; nu[i] = up[t * DI];
                nB[i] = Bp[t * 80];  nC[i] = Cp[t * 80];
            }
        }
#pragma unroll
        for (int i = 0; i < CH; ++i) {
            float dt = cdt[i];
            h = __expf(dt * Av) * h + dt * cu[i] * cB[i];
            float p = h * cC[i];
            p += __shfl_xor(p, 1, 16);
            p += __shfl_xor(p, 2, 16);
            p += __shfl_xor(p, 4, 16);
            p += __shfl_xor(p, 8, 16);
            if (n == 0) yp[(size_t)(t0 + i) * DI] = p + cu[i] * Dv;
        }
        if (more) {
#pragma unroll
            for (int i = 0; i < CH; ++i) {
                cdt[i] = ndt[i]; cu[i] = nu[i]; cB[i] = nB[i]; cC[i] = nC[i];
            }
        }
    }
}

// ---------------------------------------------------------------------------
__global__ __launch_bounds__(256) void ssmin_kernel(
    float* __restrict__ y, const float* __restrict__ xz)
{
    int id = blockIdx.x * 256 + threadIdx.x;
    int d = id % DI;
    int r = id / DI;
    float z = xz[(size_t)r * (2 * DI) + DI + d];
    y[id] = y[id] * (z / (1.f + __expf(-z)));
}

// ---------------------------------------------------------------------------
__global__ __launch_bounds__(256) void x1_kernel(
    const float* __restrict__ x, const float* __restrict__ g,
    const float* __restrict__ at, const float* __restrict__ sm,
    float* __restrict__ x1)
{
    int id = blockIdx.x * 256 + threadIdx.x;
    float gv = g[id];
    x1[id] = x[id] + gv * at[id] + (1.f - gv) * sm[id];
}

// ---------------------------------------------------------------------------
__global__ __launch_bounds__(256) void rowdot_kernel(
    const float* __restrict__ rh, const float* __restrict__ w2,
    const float* __restrict__ b2, float* __restrict__ sc)
{
    int lane = threadIdx.x & 63;
    int t = blockIdx.x * 4 + (threadIdx.x >> 6);
    const float* rp = rh + (size_t)t * 192;
    float sum = rp[lane] * w2[lane] + rp[lane + 64] * w2[lane + 64]
              + rp[lane + 128] * w2[lane + 128];
#pragma unroll
    for (int off = 32; off; off >>= 1) sum += __shfl_down(sum, off, 64);
    if (lane == 0) sc[t] = sum + b2[0];
}

// ---------------------------------------------------------------------------
__global__ __launch_bounds__(256) void topk_kernel(
    const float* __restrict__ sc, int* __restrict__ idxb)
{
    __shared__ float vals[Sc];
    __shared__ float rv[4];
    __shared__ int ri[4];
    const int b = blockIdx.x, tid = threadIdx.x;
    for (int i = tid; i < Sc; i += 256) vals[i] = sc[(size_t)b * Sc + i];
    __syncthreads();
    for (int it = 0; it < CAP; ++it) {
        float bv = -3.4e38f; int bi = 0x7fffffff;
        for (int i = tid; i < Sc; i += 256) {
            float v = vals[i];
            if (v > bv || (v == bv && i < bi)) { bv = v; bi = i; }
        }
#pragma unroll
        for (int off = 32; off; off >>= 1) {
            float ov = __shfl_down(bv, off, 64);
            int oi = __shfl_down(bi, off, 64);
            if (ov > bv || (ov == bv && oi < bi)) { bv = ov; bi = oi; }
        }
        int lane = tid & 63, wid = tid >> 6;
        if (lane == 0) { rv[wid] = bv; ri[wid] = bi; }
        __syncthreads();
        if (tid == 0) {
            float Bv = rv[0]; int Bi = ri[0];
            for (int w = 1; w < 4; ++w)
                if (rv[w] > Bv || (rv[w] == Bv && ri[w] < Bi)) { Bv = rv[w]; Bi = ri[w]; }
            idxb[b * CAP + it] = Bi;
            vals[Bi] = -3.4e38f;
        }
        __syncthreads();
    }
}

// ---------------------------------------------------------------------------
__global__ __launch_bounds__(256) void gather_kernel(
    const float* __restrict__ xn2, const int* __restrict__ idxb,
    float* __restrict__ Xsel)
{
    int i = blockIdx.x;
    int b = i >> 8;
    int t = idxb[i];
    const float* src = xn2 + ((size_t)(b * Sc + t)) * Dm;
    float* dst = Xsel + (size_t)i * Dm;
    int c = threadIdx.x;
    dst[c] = src[c]; dst[c + 256] = src[c + 256]; dst[c + 512] = src[c + 512];
}

__global__ __launch_bounds__(256) void finaladd_kernel(
    const float* __restrict__ x1, const float* __restrict__ xn2,
    float* __restrict__ out)
{
    int id = blockIdx.x * 256 + threadIdx.x;
    out[id] = x1[id] + xn2[id];
}

__global__ __launch_bounds__(256) void scatter_kernel(
    const float* __restrict__ x1, const float* __restrict__ proc,
    const int* __restrict__ idxb, float* __restrict__ out)
{
    int i = blockIdx.x;
    int b = i >> 8;
    int t = idxb[i];
    size_t ro = ((size_t)(b * Sc + t)) * Dm;
    const float* pp = proc + (size_t)i * Dm;
    int c = threadIdx.x;
    out[ro + c]       = x1[ro + c]       + pp[c];
    out[ro + c + 256] = x1[ro + c + 256] + pp[c + 256];
    out[ro + c + 512] = x1[ro + c + 512] + pp[c + 512];
}

// ---------------------------------------------------------------------------
extern "C" void kernel_launch(void* const* d_in, const int* in_sizes, int n_in,
                              void* d_out, int out_size, void* d_ws, size_t ws_size,
                              hipStream_t stream)
{
    (void)in_sizes; (void)n_in; (void)out_size; (void)ws_size;
    const float* x          = (const float*)d_in[0];
    const float* ln1_w      = (const float*)d_in[1];
    const float* ln1_b      = (const float*)d_in[2];
    const float* ln2_w      = (const float*)d_in[3];
    const float* ln2_b      = (const float*)d_in[4];
    const float* qkv_w      = (const float*)d_in[5];
    const float* attn_out_w = (const float*)d_in[6];
    const float* attn_out_b = (const float*)d_in[7];
    const float* in_proj_w  = (const float*)d_in[8];
    const float* conv_w     = (const float*)d_in[9];
    const float* conv_b     = (const float*)d_in[10];
    const float* x_proj_w   = (const float*)d_in[11];
    const float* dt_w       = (const float*)d_in[12];
    const float* dt_b       = (const float*)d_in[13];
    const float* A_log      = (const float*)d_in[14];
    const float* Dvec       = (const float*)d_in[15];
    const float* ssm_out_w  = (const float*)d_in[16];
    const float* gate_w     = (const float*)d_in[17];
    const float* gate_b     = (const float*)d_in[18];
    const float* ffn_w1     = (const float*)d_in[19];
    const float* ffn_b1     = (const float*)d_in[20];
    const float* ffn_w2     = (const float*)d_in[21];
    const float* ffn_b2     = (const float*)d_in[22];
    const float* r_w1       = (const float*)d_in[23];
    const float* r_b1       = (const float*)d_in[24];
    const float* r_w2       = (const float*)d_in[25];
    const float* r_b2       = (const float*)d_in[26];
    float* out = (float*)d_out;

    float* ws = (float*)d_ws;
    const size_t TOK = (size_t)M_ * Dm;
    float* xn   = ws;
    float* ao   = xn + TOK;
    float* y    = xn;                         // alias (scan output spans xn+ao)
    float* qkv  = ao + TOK;
    float* delta = qkv;                       // alias (after attention consumes qkv)
    float* xz   = qkv + (size_t)M_ * 2304;
    float* u    = xz + (size_t)M_ * 2 * DI;
    float* dbc  = u + (size_t)M_ * DI;
    float* attn_out = dbc + (size_t)M_ * 80;
    float* ssm_out  = attn_out + TOK;
    float* g    = ssm_out + TOK;
    float* x1   = g + TOK;
    float* xn2  = x1 + TOK;
    float* rh   = xn2 + TOK;
    float* sc   = rh + (size_t)M_ * 192;
    int*   idxb = (int*)(sc + M_);
    float* Xsel = sc + M_ + 512;
    float* Hsel = Xsel + (size_t)512 * Dm;
    float* proc = Hsel + (size_t)512 * DF;

    // Attention partial buffers: arenas provably dead until combine consumes
    // them (po: attn_out..x1 arena = 4*TOK = NCH*NQ*64 exactly, first written
    // by gemm step 5; pm/pl: rh arena, first written by router gemm step 17).
    float* po  = attn_out;
    float* pmb = rh;
    float* plb = rh + (size_t)NCH * NQ;

    // 1. LN1
    ln_kernel<<<M_, 256, 0, stream>>>(x, ln1_w, ln1_b, xn);
    // 2. QKV projection
    gemm_kernel<<<dim3(18, 32), 256, 0, stream>>>(xn, Dm, qkv_w, nullptr, qkv, M_, 2304, 768, 0, 0);
    // 3. RoPE
    rope_kernel<<<(Bc * Sc * Hc * 32) / 256, 256, 0, stream>>>(qkv);
    // 4. Attention: key-split partials + combine
    attn_partial_kernel<<<dim3(Sc / 256, Bc * Hc, NCH), 256, 0, stream>>>(qkv, po, pmb, plb);
    attn_combine_kernel<<<NQ / 4, 256, 0, stream>>>(po, pmb, plb, ao);
    // 5. attn_out projection (overwrites po arena start — po is dead now)
    gemm_kernel<<<dim3(6, 32), 256, 0, stream>>>(ao, Dm, attn_out_w, attn_out_b, attn_out, M_, 768, 768, 0, 0);
    // 6. in_proj
    gemm_kernel<<<dim3(24, 32), 256, 0, stream>>>(xn, Dm, in_proj_w, nullptr, xz, M_, 2 * DI, 768, 0, 0);
    // 7. causal conv + SiLU
    conv_silu_kernel<<<(M_ * DI) / 256, 256, 0, stream>>>(xz, conv_w, conv_b, u);
    // 8. x_proj
    gemm_kernel<<<dim3(1, 32), 256, 0, stream>>>(u, DI, x_proj_w, nullptr, dbc, M_, 80, 1536, 0, 0);
    // 9. delta
    gemm_kernel<<<dim3(12, 32), 256, 0, stream>>>(dbc, 80, dt_w, dt_b, delta, M_, DI, DTR, 1, 0);
    // 10. scan
    scan_kernel<<<(Bc * DI * NST) / 256, 256, 0, stream>>>(delta, u, dbc, A_log, Dvec, y);
    // 11. y *= silu(z)
    ssmin_kernel<<<(M_ * DI) / 256, 256, 0, stream>>>(y, xz);
    // 12. ssm_out
    gemm_kernel<<<dim3(6, 32), 256, 0, stream>>>(y, DI, ssm_out_w, nullptr, ssm_out, M_, 768, 1536, 0, 0);
    // 13/14. gate
    gemm_kernel<<<dim3(6, 32), 256, 0, stream>>>(attn_out, Dm, gate_w, nullptr, g, M_, 768, 768, 0, 0);
    gemm_kernel<<<dim3(6, 32), 256, 0, stream>>>(ssm_out, Dm, gate_w + (size_t)768 * 768, gate_b, g, M_, 768, 768, 2, 1);
    // 15. x1
    x1_kernel<<<(M_ * Dm) / 256, 256, 0, stream>>>(x, g, attn_out, ssm_out, x1);
    // 16. LN2
    ln_kernel<<<M_, 256, 0, stream>>>(x1, ln2_w, ln2_b, xn2);
    // 17. router hidden (overwrites pm/pl arena — dead since combine)
    gemm_kernel<<<dim3(2, 32), 256, 0, stream>>>(xn2, Dm, r_w1, r_b1, rh, M_, 192, 768, 3, 0);
    // 18. scores
    rowdot_kernel<<<M_ / 4, 256, 0, stream>>>(rh, r_w2, r_b2, sc);
    // 19. top-k
    topk_kernel<<<Bc, 256, 0, stream>>>(sc, idxb);
    // 20. gather
    gather_kernel<<<Bc * CAP, 256, 0, stream>>>(xn2, idxb, Xsel);
    // 21. FFN1
    gemm_kernel<<<dim3(24, 4), 256, 0, stream>>>(Xsel, Dm, ffn_w1, ffn_b1, Hsel, Bc * CAP, DF, 768, 4, 0);
    // 22. FFN2
    gemm_kernel<<<dim3(6, 4), 256, 0, stream>>>(Hsel, DF, ffn_w2, ffn_b2, proc, Bc * CAP, 768, DF, 0, 0);
    // 23. out = x1 + xn2
    finaladd_kernel<<<(M_ * Dm) / 256, 256, 0, stream>>>(x1, xn2, out);
    // 24. scatter
    scatter_kernel<<<Bc * CAP, 256, 0, stream>>>(x1, proc, idxb, out);
}

// Round 5
// 4228.046 us; speedup vs baseline: 1.0131x; 1.0131x over previous
//
#include <hip/hip_runtime.h>
#include <cstdint>
#include <cstddef>

// Problem constants
constexpr int Bc   = 2;
constexpr int Sc   = 2048;
constexpr int Dm   = 768;
constexpr int Hc   = 12;
constexpr int HD   = 64;
constexpr int DI   = 1536;
constexpr int NST  = 16;
constexpr int DTR  = 48;
constexpr int CAP  = 256;   // 0.125 * S
constexpr int DF   = 3072;
constexpr int M_   = Bc * Sc;  // 4096 tokens
constexpr int NQ   = Bc * Hc * Sc;  // 49152 (b,h,s) query rows
constexpr int NCH  = 4;             // key chunks

// ---------------------------------------------------------------------------
// Activation codes: 0 none, 1 softplus, 2 sigmoid, 3 relu, 4 gelu(exact)
__device__ __forceinline__ float apply_act(float v, int act) {
    switch (act) {
        case 1: return (v > 20.f) ? v : log1pf(__expf(v));
        case 2: return 1.f / (1.f + __expf(-v));
        case 3: return fmaxf(v, 0.f);
        case 4: return 0.5f * v * (1.f + erff(v * 0.70710678118654752f));
        default: return v;
    }
}

// ---------------------------------------------------------------------------
// Generic fp32 GEMM: C[M,N] = act(acc*C + A[M,K](lda) @ W[K,N] + bias)
// __launch_bounds__(256,2): VGPR cap 256. Real demand ~130+ regs (64 acc +
// 16 frag + 16 staging + addressing); the (256,4) cap of 128 still spilled
// (round-4 neutral). Template ID gives each call site a distinct kernel name
// for per-GEMM rocprof attribution.
template <int ID>
__global__ __launch_bounds__(256, 2) void gemm_kernel(
    const float* __restrict__ A, int lda,
    const float* __restrict__ W,
    const float* __restrict__ bias,
    float* __restrict__ C,
    int M, int N, int K, int act, int accflag)
{
    __shared__ float As[16][132];
    __shared__ float Bs[16][132];
    const int tid = threadIdx.x;
    const int bm = blockIdx.y * 128;
    const int bn = blockIdx.x * 128;
    const int tx = tid & 15, ty = tid >> 4;

    float acc[8][8];
#pragma unroll
    for (int i = 0; i < 8; ++i)
#pragma unroll
        for (int j = 0; j < 8; ++j) acc[i][j] = 0.f;

    for (int k0 = 0; k0 < K; k0 += 16) {
#pragma unroll
        for (int i = 0; i < 2; ++i) {
            int f = tid + 256 * i;
            int row = f >> 2;
            int kc = (f & 3) * 4;
            const float* ap = A + (size_t)(bm + row) * lda + (k0 + kc);
            float4 v = *(const float4*)ap;
            As[kc + 0][row] = v.x; As[kc + 1][row] = v.y;
            As[kc + 2][row] = v.z; As[kc + 3][row] = v.w;
        }
#pragma unroll
        for (int i = 0; i < 2; ++i) {
            int f = tid + 256 * i;
            int row = f >> 5;
            int col = (f & 31) * 4;
            int gn = bn + col;
            const float* wp = W + (size_t)(k0 + row) * N + gn;
            float4 v;
            if (gn + 3 < N) v = *(const float4*)wp;
            else {
                v.x = (gn + 0 < N) ? wp[0] : 0.f;
                v.y = (gn + 1 < N) ? wp[1] : 0.f;
                v.z = (gn + 2 < N) ? wp[2] : 0.f;
                v.w = (gn + 3 < N) ? wp[3] : 0.f;
            }
            *(float4*)&Bs[row][col] = v;
        }
        __syncthreads();
#pragma unroll
        for (int kk = 0; kk < 16; ++kk) {
            float a[8], b[8];
            *(float4*)&a[0] = *(const float4*)&As[kk][ty * 4];
            *(float4*)&a[4] = *(const float4*)&As[kk][64 + ty * 4];
            *(float4*)&b[0] = *(const float4*)&Bs[kk][tx * 4];
            *(float4*)&b[4] = *(const float4*)&Bs[kk][64 + tx * 4];
#pragma unroll
            for (int i = 0; i < 8; ++i)
#pragma unroll
                for (int j = 0; j < 8; ++j)
                    acc[i][j] = fmaf(a[i], b[j], acc[i][j]);
        }
        __syncthreads();
    }

#pragma unroll
    for (int ii = 0; ii < 8; ++ii) {
        int row = bm + ((ii < 4) ? (ty * 4 + ii) : (64 + ty * 4 + ii - 4));
#pragma unroll
        for (int jj = 0; jj < 8; ++jj) {
            int col = bn + ((jj < 4) ? (tx * 4 + jj) : (64 + tx * 4 + jj - 4));
            if (col < N) {
                size_t cidx = (size_t)row * N + col;
                float v = acc[ii][jj];
                if (accflag) v += C[cidx];
                if (bias) v += bias[col];
                C[cidx] = apply_act(v, act);
            }
        }
    }
}

// ---------------------------------------------------------------------------
__global__ __launch_bounds__(256) void ln_kernel(
    const float* __restrict__ x, const float* __restrict__ w,
    const float* __restrict__ b, float* __restrict__ out)
{
    const int row = blockIdx.x, tid = threadIdx.x;
    const float* xp = x + (size_t)row * Dm;
    float v0 = xp[tid], v1 = xp[tid + 256], v2 = xp[tid + 512];
    float s1 = v0 + v1 + v2;
    float s2 = v0 * v0 + v1 * v1 + v2 * v2;
#pragma unroll
    for (int off = 32; off; off >>= 1) {
        s1 += __shfl_down(s1, off, 64);
        s2 += __shfl_down(s2, off, 64);
    }
    __shared__ float r1[4], r2[4];
    int wid = tid >> 6, lane = tid & 63;
    if (lane == 0) { r1[wid] = s1; r2[wid] = s2; }
    __syncthreads();
    s1 = r1[0] + r1[1] + r1[2] + r1[3];
    s2 = r2[0] + r2[1] + r2[2] + r2[3];
    float mu = s1 * (1.f / 768.f);
    float var = s2 * (1.f / 768.f) - mu * mu;
    float rstd = rsqrtf(var + 1e-5f);
    float* op = out + (size_t)row * Dm;
    op[tid]       = (v0 - mu) * rstd * w[tid]       + b[tid];
    op[tid + 256] = (v1 - mu) * rstd * w[tid + 256] + b[tid + 256];
    op[tid + 512] = (v2 - mu) * rstd * w[tid + 512] + b[tid + 512];
}

// ---------------------------------------------------------------------------
__global__ __launch_bounds__(256) void rope_kernel(float* __restrict__ qkv)
{
    int id = blockIdx.x * 256 + threadIdx.x;   // B*S*H*32
    int i = id & 31;
    int h = (id >> 5) % Hc;
    int r = id / (32 * Hc);        // b*S + s
    int s = r & (Sc - 1);
    float inv = powf(10000.f, -(float)(2 * i) * (1.f / 64.f));
    float f = (float)s * inv;
    float sn, cs;
    sincosf(f, &sn, &cs);
    float* base = qkv + (size_t)r * 2304 + h * 64 + i;
    float q1 = base[0], q2 = base[32];
    base[0]  = q1 * cs - q2 * sn;
    base[32] = q1 * sn + q2 * cs;
    float* kb = base + Dm;
    float k1 = kb[0], k2 = kb[32];
    kb[0]  = k1 * cs - k2 * sn;
    kb[32] = k1 * sn + k2 * cs;
}

// ---------------------------------------------------------------------------
// Flash-attention partial over a 512-key chunk.
__global__ __launch_bounds__(256) void attn_partial_kernel(
    const float* __restrict__ qkv, float* __restrict__ po,
    float* __restrict__ pm, float* __restrict__ pl)
{
    __shared__ float Kt[64][64];
    __shared__ float Vt[64][64];
    const int tid = threadIdx.x;
    const int bh = blockIdx.y;              // 0..23
    const int b = bh / Hc, h = bh % Hc;
    const int chunk = blockIdx.z;           // 0..3
    const int u = tid & 1;
    const int pr = tid >> 1;                // 0..127
    const int sA = blockIdx.x * 256 + 2 * pr;

    float qA[32], qB[32], oA[32], oB[32];
    {
        const float* qpA = qkv + ((size_t)(b * Sc + sA)) * 2304 + h * 64 + 32 * u;
        const float* qpB = qpA + 2304;
#pragma unroll
        for (int i = 0; i < 8; ++i) {
            float4 a = *(const float4*)(qpA + 4 * i);
            float4 bb = *(const float4*)(qpB + 4 * i);
            qA[4*i+0] = a.x * 0.125f; qA[4*i+1] = a.y * 0.125f;
            qA[4*i+2] = a.z * 0.125f; qA[4*i+3] = a.w * 0.125f;
            qB[4*i+0] = bb.x * 0.125f; qB[4*i+1] = bb.y * 0.125f;
            qB[4*i+2] = bb.z * 0.125f; qB[4*i+3] = bb.w * 0.125f;
        }
    }
#pragma unroll
    for (int i = 0; i < 32; ++i) { oA[i] = 0.f; oB[i] = 0.f; }
    float mA = -1e30f, lA = 0.f, mB = -1e30f, lB = 0.f;

    const int k0base = chunk * 512;
    for (int kt = 0; kt < 512; kt += 64) {
#pragma unroll
        for (int i = 0; i < 8; ++i) {
            int f = tid + 256 * i;          // 0..2047
            int isV = f >> 10;              // 0:K 1:V
            int g = f & 1023;
            int row = g >> 4;
            int c4 = (g & 15) * 4;
            const float* src = qkv + ((size_t)(b * Sc + k0base + kt + row)) * 2304
                             + Dm + isV * Dm + h * 64 + c4;
            if (isV) *(float4*)&Vt[row][c4] = *(const float4*)src;
            else     *(float4*)&Kt[row][c4] = *(const float4*)src;
        }
        __syncthreads();

#pragma unroll 1
        for (int j0 = 0; j0 < 64; j0 += 8) {
            float pa[8], pb[8];
#pragma unroll
            for (int jj = 0; jj < 8; ++jj) {
                const float* kr = &Kt[j0 + jj][32 * u];
                float da0 = 0.f, da1 = 0.f, db0 = 0.f, db1 = 0.f;
#pragma unroll
                for (int c = 0; c < 4; ++c) {
                    float4 k1v = *(const float4*)(kr + 8 * c);
                    float4 k2v = *(const float4*)(kr + 8 * c + 4);
                    da0 += qA[8*c+0]*k1v.x + qA[8*c+1]*k1v.y + qA[8*c+2]*k1v.z + qA[8*c+3]*k1v.w;
                    da1 += qA[8*c+4]*k2v.x + qA[8*c+5]*k2v.y + qA[8*c+6]*k2v.z + qA[8*c+7]*k2v.w;
                    db0 += qB[8*c+0]*k1v.x + qB[8*c+1]*k1v.y + qB[8*c+2]*k1v.z + qB[8*c+3]*k1v.w;
                    db1 += qB[8*c+4]*k2v.x + qB[8*c+5]*k2v.y + qB[8*c+6]*k2v.z + qB[8*c+7]*k2v.w;
                }
                float da = da0 + da1;
                float db = db0 + db1;
                da += __shfl_xor(da, 1, 64);
                db += __shfl_xor(db, 1, 64);
                pa[jj] = da; pb[jj] = db;
            }
            float cmA = pa[0], cmB = pb[0];
#pragma unroll
            for (int jj = 1; jj < 8; ++jj) {
                cmA = fmaxf(cmA, pa[jj]); cmB = fmaxf(cmB, pb[jj]);
            }
            float nmA = fmaxf(mA, cmA), nmB = fmaxf(mB, cmB);
            float sfA = __expf(mA - nmA), sfB = __expf(mB - nmB);
            mA = nmA; mB = nmB;
            lA *= sfA; lB *= sfB;
#pragma unroll
            for (int i = 0; i < 32; ++i) { oA[i] *= sfA; oB[i] *= sfB; }
#pragma unroll
            for (int jj = 0; jj < 8; ++jj) {
                pa[jj] = __expf(pa[jj] - mA); lA += pa[jj];
                pb[jj] = __expf(pb[jj] - mB); lB += pb[jj];
            }
#pragma unroll
            for (int jj = 0; jj < 8; ++jj) {
                const float* vr = &Vt[j0 + jj][32 * u];
                float paj = pa[jj], pbj = pb[jj];
#pragma unroll
                for (int c = 0; c < 8; ++c) {
                    float4 vv = *(const float4*)(vr + 4 * c);
                    oA[4*c+0] += paj * vv.x; oA[4*c+1] += paj * vv.y;
                    oA[4*c+2] += paj * vv.z; oA[4*c+3] += paj * vv.w;
                    oB[4*c+0] += pbj * vv.x; oB[4*c+1] += pbj * vv.y;
                    oB[4*c+2] += pbj * vv.z; oB[4*c+3] += pbj * vv.w;
                }
            }
        }
        __syncthreads();
    }

    const size_t qiA = (size_t)bh * Sc + sA;
    const size_t qiB = qiA + 1;
    float* poA = po + ((size_t)chunk * NQ + qiA) * 64 + 32 * u;
    float* poB = po + ((size_t)chunk * NQ + qiB) * 64 + 32 * u;
#pragma unroll
    for (int i = 0; i < 8; ++i) {
        float4 t;
        t.x = oA[4*i+0]; t.y = oA[4*i+1]; t.z = oA[4*i+2]; t.w = oA[4*i+3];
        *(float4*)(poA + 4 * i) = t;
        t.x = oB[4*i+0]; t.y = oB[4*i+1]; t.z = oB[4*i+2]; t.w = oB[4*i+3];
        *(float4*)(poB + 4 * i) = t;
    }
    if (u == 0) {
        pm[(size_t)chunk * NQ + qiA] = mA;
        pl[(size_t)chunk * NQ + qiA] = lA;
        pm[(size_t)chunk * NQ + qiB] = mB;
        pl[(size_t)chunk * NQ + qiB] = lB;
    }
}

// Merge NCH partials -> ao (B,S,Dm). Block = 4 queries x 64 dims.
__global__ __launch_bounds__(256) void attn_combine_kernel(
    const float* __restrict__ po, const float* __restrict__ pm,
    const float* __restrict__ pl, float* __restrict__ ao)
{
    const int tid = threadIdx.x;
    const int d = tid & 63;
    const int qi = blockIdx.x * 4 + (tid >> 6);   // bh*Sc + s
    const int bh = qi >> 11;
    const int s = qi & (Sc - 1);
    const int b = bh / Hc, h = bh % Hc;
    float m0 = pm[qi], m1 = pm[NQ + qi], m2 = pm[2*NQ + qi], m3 = pm[3*NQ + qi];
    float M = fmaxf(fmaxf(m0, m1), fmaxf(m2, m3));
    float w0 = __expf(m0 - M), w1 = __expf(m1 - M);
    float w2 = __expf(m2 - M), w3 = __expf(m3 - M);
    float l = w0 * pl[qi] + w1 * pl[NQ + qi] + w2 * pl[2*NQ + qi] + w3 * pl[3*NQ + qi];
    float o = w0 * po[(size_t)qi * 64 + d]
            + w1 * po[((size_t)NQ + qi) * 64 + d]
            + w2 * po[((size_t)2*NQ + qi) * 64 + d]
            + w3 * po[((size_t)3*NQ + qi) * 64 + d];
    ao[((size_t)(b * Sc + s)) * Dm + h * 64 + d] = o / l;
}

// ---------------------------------------------------------------------------
__global__ __launch_bounds__(256) void conv_silu_kernel(
    const float* __restrict__ xz, const float* __restrict__ cw,
    const float* __restrict__ cb, float* __restrict__ u)
{
    int id = blockIdx.x * 256 + threadIdx.x;   // B*S*DI
    int d = id % DI;
    int r = id / DI;
    int s = r & (Sc - 1);
    int b = r >> 11;
    float acc = cb[d];
#pragma unroll
    for (int j = 0; j < 4; ++j) {
        int sp = s + j - 3;
        if (sp >= 0)
            acc += xz[((size_t)(b * Sc + sp)) * (2 * DI) + d] * cw[d * 4 + j];
    }
    u[id] = acc / (1.f + __expf(-acc));
}

// ---------------------------------------------------------------------------
__global__ __launch_bounds__(256) void scan_kernel(
    const float* __restrict__ delta, const float* __restrict__ u,
    const float* __restrict__ dbc, const float* __restrict__ A_log,
    const float* __restrict__ Dp, float* __restrict__ y)
{
    int gid = blockIdx.x * 256 + threadIdx.x;
    int n = gid & 15;
    int ch = gid >> 4;
    int b = ch / DI;
    int dd = ch - b * DI;
    float Av = -__expf(A_log[dd * NST + n]);
    float Dv = Dp[dd];
    const float* dp = delta + (size_t)b * Sc * DI + dd;
    const float* up = u     + (size_t)b * Sc * DI + dd;
    const float* Bp = dbc   + (size_t)b * Sc * 80 + DTR + n;
    const float* Cp = Bp + NST;
    float* yp = y + (size_t)b * Sc * DI + dd;

    float h = 0.f;
    constexpr int CH = 8;
    float cdt[CH], cu[CH], cB[CH], cC[CH];
    float ndt[CH], nu[CH], nB[CH], nC[CH];
#pragma unroll
    for (int i = 0; i < CH; ++i) {
        cdt[i] = dp[(size_t)i * DI]; cu[i] = up[(size_t)i * DI];
        cB[i] = Bp[(size_t)i * 80];  cC[i] = Cp[(size_t)i * 80];
    }
    for (int t0 = 0; t0 < Sc; t0 += CH) {
        bool more = (t0 + CH < Sc);
        if (more) {
#pragma unroll
            for (int i = 0; i < CH; ++i) {
                size_t t = t0 + CH + i;
                ndt[i] = dp[t * DI]; nu[i] = up[t * DI];
                nB[i] = Bp[t * 80];  nC[i] = Cp[t * 80];
            }
        }
#pragma unroll
        for (int i = 0; i < CH; ++i) {
            float dt = cdt[i];
            h = __expf(dt * Av) * h + dt * cu[i] * cB[i];
            float p = h * cC[i];
            p += __shfl_xor(p, 1, 16);
            p += __shfl_xor(p, 2, 16);
            p += __shfl_xor(p, 4, 16);
            p += __shfl_xor(p, 8, 16);
            if (n == 0) yp[(size_t)(t0 + i) * DI] = p + cu[i] * Dv;
        }
        if (more) {
#pragma unroll
            for (int i = 0; i < CH; ++i) {
                cdt[i] = ndt[i]; cu[i] = nu[i]; cB[i] = nB[i]; cC[i] = nC[i];
            }
        }
    }
}

// ---------------------------------------------------------------------------
__global__ __launch_bounds__(256) void ssmin_kernel(
    float* __restrict__ y, const float* __restrict__ xz)
{
    int id = blockIdx.x * 256 + threadIdx.x;
    int d = id % DI;
    int r = id / DI;
    float z = xz[(size_t)r * (2 * DI) + DI + d];
    y[id] = y[id] * (z / (1.f + __expf(-z)));
}

// ---------------------------------------------------------------------------
__global__ __launch_bounds__(256) void x1_kernel(
    const float* __restrict__ x, const float* __restrict__ g,
    const float* __restrict__ at, const float* __restrict__ sm,
    float* __restrict__ x1)
{
    int id = blockIdx.x * 256 + threadIdx.x;
    float gv = g[id];
    x1[id] = x[id] + gv * at[id] + (1.f - gv) * sm[id];
}

// ---------------------------------------------------------------------------
__global__ __launch_bounds__(256) void rowdot_kernel(
    const float* __restrict__ rh, const float* __restrict__ w2,
    const float* __restrict__ b2, float* __restrict__ sc)
{
    int lane = threadIdx.x & 63;
    int t = blockIdx.x * 4 + (threadIdx.x >> 6);
    const float* rp = rh + (size_t)t * 192;
    float sum = rp[lane] * w2[lane] + rp[lane + 64] * w2[lane + 64]
              + rp[lane + 128] * w2[lane + 128];
#pragma unroll
    for (int off = 32; off; off >>= 1) sum += __shfl_down(sum, off, 64);
    if (lane == 0) sc[t] = sum + b2[0];
}

// ---------------------------------------------------------------------------
__global__ __launch_bounds__(256) void topk_kernel(
    const float* __restrict__ sc, int* __restrict__ idxb)
{
    __shared__ float vals[Sc];
    __shared__ float rv[4];
    __shared__ int ri[4];
    const int b = blockIdx.x, tid = threadIdx.x;
    for (int i = tid; i < Sc; i += 256) vals[i] = sc[(size_t)b * Sc + i];
    __syncthreads();
    for (int it = 0; it < CAP; ++it) {
        float bv = -3.4e38f; int bi = 0x7fffffff;
        for (int i = tid; i < Sc; i += 256) {
            float v = vals[i];
            if (v > bv || (v == bv && i < bi)) { bv = v; bi = i; }
        }
#pragma unroll
        for (int off = 32; off; off >>= 1) {
            float ov = __shfl_down(bv, off, 64);
            int oi = __shfl_down(bi, off, 64);
            if (ov > bv || (ov == bv && oi < bi)) { bv = ov; bi = oi; }
        }
        int lane = tid & 63, wid = tid >> 6;
        if (lane == 0) { rv[wid] = bv; ri[wid] = bi; }
        __syncthreads();
        if (tid == 0) {
            float Bv = rv[0]; int Bi = ri[0];
            for (int w = 1; w < 4; ++w)
                if (rv[w] > Bv || (rv[w] == Bv && ri[w] < Bi)) { Bv = rv[w]; Bi = ri[w]; }
            idxb[b * CAP + it] = Bi;
            vals[Bi] = -3.4e38f;
        }
        __syncthreads();
    }
}

// ---------------------------------------------------------------------------
__global__ __launch_bounds__(256) void gather_kernel(
    const float* __restrict__ xn2, const int* __restrict__ idxb,
    float* __restrict__ Xsel)
{
    int i = blockIdx.x;
    int b = i >> 8;
    int t = idxb[i];
    const float* src = xn2 + ((size_t)(b * Sc + t)) * Dm;
    float* dst = Xsel + (size_t)i * Dm;
    int c = threadIdx.x;
    dst[c] = src[c]; dst[c + 256] = src[c + 256]; dst[c + 512] = src[c + 512];
}

__global__ __launch_bounds__(256) void finaladd_kernel(
    const float* __restrict__ x1, const float* __restrict__ xn2,
    float* __restrict__ out)
{
    int id = blockIdx.x * 256 + threadIdx.x;
    out[id] = x1[id] + xn2[id];
}

__global__ __launch_bounds__(256) void scatter_kernel(
    const float* __restrict__ x1, const float* __restrict__ proc,
    const int* __restrict__ idxb, float* __restrict__ out)
{
    int i = blockIdx.x;
    int b = i >> 8;
    int t = idxb[i];
    size_t ro = ((size_t)(b * Sc + t)) * Dm;
    const float* pp = proc + (size_t)i * Dm;
    int c = threadIdx.x;
    out[ro + c]       = x1[ro + c]       + pp[c];
    out[ro + c + 256] = x1[ro + c + 256] + pp[c + 256];
    out[ro + c + 512] = x1[ro + c + 512] + pp[c + 512];
}

// ---------------------------------------------------------------------------
extern "C" void kernel_launch(void* const* d_in, const int* in_sizes, int n_in,
                              void* d_out, int out_size, void* d_ws, size_t ws_size,
                              hipStream_t stream)
{
    (void)in_sizes; (void)n_in; (void)out_size; (void)ws_size;
    const float* x          = (const float*)d_in[0];
    const float* ln1_w      = (const float*)d_in[1];
    const float* ln1_b      = (const float*)d_in[2];
    const float* ln2_w      = (const float*)d_in[3];
    const float* ln2_b      = (const float*)d_in[4];
    const float* qkv_w      = (const float*)d_in[5];
    const float* attn_out_w = (const float*)d_in[6];
    const float* attn_out_b = (const float*)d_in[7];
    const float* in_proj_w  = (const float*)d_in[8];
    const float* conv_w     = (const float*)d_in[9];
    const float* conv_b     = (const float*)d_in[10];
    const float* x_proj_w   = (const float*)d_in[11];
    const float* dt_w       = (const float*)d_in[12];
    const float* dt_b       = (const float*)d_in[13];
    const float* A_log      = (const float*)d_in[14];
    const float* Dvec       = (const float*)d_in[15];
    const float* ssm_out_w  = (const float*)d_in[16];
    const float* gate_w     = (const float*)d_in[17];
    const float* gate_b     = (const float*)d_in[18];
    const float* ffn_w1     = (const float*)d_in[19];
    const float* ffn_b1     = (const float*)d_in[20];
    const float* ffn_w2     = (const float*)d_in[21];
    const float* ffn_b2     = (const float*)d_in[22];
    const float* r_w1       = (const float*)d_in[23];
    const float* r_b1       = (const float*)d_in[24];
    const float* r_w2       = (const float*)d_in[25];
    const float* r_b2       = (const float*)d_in[26];
    float* out = (float*)d_out;

    float* ws = (float*)d_ws;
    const size_t TOK = (size_t)M_ * Dm;
    float* xn   = ws;
    float* ao   = xn + TOK;
    float* y    = xn;                         // alias (scan output spans xn+ao)
    float* qkv  = ao + TOK;
    float* delta = qkv;                       // alias (after attention consumes qkv)
    float* xz   = qkv + (size_t)M_ * 2304;
    float* u    = xz + (size_t)M_ * 2 * DI;
    float* dbc  = u + (size_t)M_ * DI;
    float* attn_out = dbc + (size_t)M_ * 80;
    float* ssm_out  = attn_out + TOK;
    float* g    = ssm_out + TOK;
    float* x1   = g + TOK;
    float* xn2  = x1 + TOK;
    float* rh   = xn2 + TOK;
    float* sc   = rh + (size_t)M_ * 192;
    int*   idxb = (int*)(sc + M_);
    float* Xsel = sc + M_ + 512;
    float* Hsel = Xsel + (size_t)512 * Dm;
    float* proc = Hsel + (size_t)512 * DF;

    // Attention partial buffers (arenas dead until combine consumes them)
    float* po  = attn_out;
    float* pmb = rh;
    float* plb = rh + (size_t)NCH * NQ;

    // 1. LN1
    ln_kernel<<<M_, 256, 0, stream>>>(x, ln1_w, ln1_b, xn);
    // 2. QKV projection
    gemm_kernel<0><<<dim3(18, 32), 256, 0, stream>>>(xn, Dm, qkv_w, nullptr, qkv, M_, 2304, 768, 0, 0);
    // 3. RoPE
    rope_kernel<<<(Bc * Sc * Hc * 32) / 256, 256, 0, stream>>>(qkv);
    // 4. Attention: key-split partials + combine
    attn_partial_kernel<<<dim3(Sc / 256, Bc * Hc, NCH), 256, 0, stream>>>(qkv, po, pmb, plb);
    attn_combine_kernel<<<NQ / 4, 256, 0, stream>>>(po, pmb, plb, ao);
    // 5. attn_out projection
    gemm_kernel<1><<<dim3(6, 32), 256, 0, stream>>>(ao, Dm, attn_out_w, attn_out_b, attn_out, M_, 768, 768, 0, 0);
    // 6. in_proj
    gemm_kernel<2><<<dim3(24, 32), 256, 0, stream>>>(xn, Dm, in_proj_w, nullptr, xz, M_, 2 * DI, 768, 0, 0);
    // 7. causal conv + SiLU
    conv_silu_kernel<<<(M_ * DI) / 256, 256, 0, stream>>>(xz, conv_w, conv_b, u);
    // 8. x_proj
    gemm_kernel<3><<<dim3(1, 32), 256, 0, stream>>>(u, DI, x_proj_w, nullptr, dbc, M_, 80, 1536, 0, 0);
    // 9. delta
    gemm_kernel<4><<<dim3(12, 32), 256, 0, stream>>>(dbc, 80, dt_w, dt_b, delta, M_, DI, DTR, 1, 0);
    // 10. scan
    scan_kernel<<<(Bc * DI * NST) / 256, 256, 0, stream>>>(delta, u, dbc, A_log, Dvec, y);
    // 11. y *= silu(z)
    ssmin_kernel<<<(M_ * DI) / 256, 256, 0, stream>>>(y, xz);
    // 12. ssm_out
    gemm_kernel<5><<<dim3(6, 32), 256, 0, stream>>>(y, DI, ssm_out_w, nullptr, ssm_out, M_, 768, 1536, 0, 0);
    // 13/14. gate
    gemm_kernel<6><<<dim3(6, 32), 256, 0, stream>>>(attn_out, Dm, gate_w, nullptr, g, M_, 768, 768, 0, 0);
    gemm_kernel<7><<<dim3(6, 32), 256, 0, stream>>>(ssm_out, Dm, gate_w + (size_t)768 * 768, gate_b, g, M_, 768, 768, 2, 1);
    // 15. x1
    x1_kernel<<<(M_ * Dm) / 256, 256, 0, stream>>>(x, g, attn_out, ssm_out, x1);
    // 16. LN2
    ln_kernel<<<M_, 256, 0, stream>>>(x1, ln2_w, ln2_b, xn2);
    // 17. router hidden
    gemm_kernel<8><<<dim3(2, 32), 256, 0, stream>>>(xn2, Dm, r_w1, r_b1, rh, M_, 192, 768, 3, 0);
    // 18. scores
    rowdot_kernel<<<M_ / 4, 256, 0, stream>>>(rh, r_w2, r_b2, sc);
    // 19. top-k
    topk_kernel<<<Bc, 256, 0, stream>>>(sc, idxb);
    // 20. gather
    gather_kernel<<<Bc * CAP, 256, 0, stream>>>(xn2, idxb, Xsel);
    // 21. FFN1
    gemm_kernel<9><<<dim3(24, 4), 256, 0, stream>>>(Xsel, Dm, ffn_w1, ffn_b1, Hsel, Bc * CAP, DF, 768, 4, 0);
    // 22. FFN2
    gemm_kernel<10><<<dim3(6, 4), 256, 0, stream>>>(Hsel, DF, ffn_w2, ffn_b2, proc, Bc * CAP, 768, DF, 0, 0);
    // 23. out = x1 + xn2
    finaladd_kernel<<<(M_ * Dm) / 256, 256, 0, stream>>>(x1, xn2, out);
    // 24. scatter
    scatter_kernel<<<Bc * CAP, 256, 0, stream>>>(x1, proc, idxb, out);
}

// Round 6
// 3919.651 us; speedup vs baseline: 1.0928x; 1.0787x over previous
//
#include <hip/hip_runtime.h>
#include <cstdint>
#include <cstddef>

// Problem constants
constexpr int Bc   = 2;
constexpr int Sc   = 2048;
constexpr int Dm   = 768;
constexpr int Hc   = 12;
constexpr int HD   = 64;
constexpr int DI   = 1536;
constexpr int NST  = 16;
constexpr int DTR  = 48;
constexpr int CAP  = 256;   // 0.125 * S
constexpr int DF   = 3072;
constexpr int M_   = Bc * Sc;  // 4096 tokens
constexpr int NQ   = Bc * Hc * Sc;  // 49152 (b,h,s) query rows
constexpr int NCH  = 4;             // key chunks

typedef __attribute__((ext_vector_type(8))) short bf16x8;   // 8 bf16 in 4 VGPRs
typedef __attribute__((ext_vector_type(4))) float f32x4;    // MFMA accumulator

// ---------------------------------------------------------------------------
// Activation codes: 0 none, 1 softplus, 2 sigmoid, 3 relu, 4 gelu(exact)
__device__ __forceinline__ float apply_act(float v, int act) {
    switch (act) {
        case 1: return (v > 20.f) ? v : log1pf(__expf(v));
        case 2: return 1.f / (1.f + __expf(-v));
        case 3: return fmaxf(v, 0.f);
        case 4: return 0.5f * v * (1.f + erff(v * 0.70710678118654752f));
        default: return v;
    }
}

__device__ __forceinline__ short f2bf(float x) {   // RNE float->bf16 bits
    unsigned u = __float_as_uint(x);
    unsigned r = u + 0x7FFFu + ((u >> 16) & 1u);
    return (short)(r >> 16);
}
__device__ __forceinline__ float bf2f(short h) {
    return __uint_as_float(((unsigned)(unsigned short)h) << 16);
}

// ---------------------------------------------------------------------------
// bf16x3-split MFMA GEMM: C[M,N] = act(acc*C + A[M,K](lda) @ W[K,N] + bias)
// A,W fp32 in memory; split on the fly: x = hi + lo (both bf16). Accumulate
// Ahi*Whi + Ahi*Wlo + Alo*Whi in fp32 via v_mfma_f32_16x16x32_bf16
// (error ~2^-18 relative — fp32-class for this problem's tolerances).
// Tile 128x128xBK32, 256 thr = 4 waves of 64x64. Fragments stored
// pre-swizzled in lane order (16B/lane contiguous ds_read_b128).
// Layouts (m89/m118-verified): A: m=lane&15,k=quad*8+j; B: k=quad*8+j,
// n=lane&15; D: col=lane&15,row=quad*4+reg.
// M must be a multiple of 128; N,K arbitrary (zero-filled tails).
template <int ID>
__global__ __launch_bounds__(256, 2) void gemm_mfma(
    const float* __restrict__ A, int lda,
    const float* __restrict__ W,
    const float* __restrict__ bias,
    float* __restrict__ C,
    int M, int N, int K, int act, int accflag)
{
    constexpr int BK = 32;
    // fragment buffers, lane-order: [tile(8)][lane(64)][j(8)] shorts = 8KB each
    __shared__ __attribute__((aligned(16))) short AhS[4096];
    __shared__ __attribute__((aligned(16))) short AlS[4096];
    __shared__ __attribute__((aligned(16))) short BhS[4096];
    __shared__ __attribute__((aligned(16))) short BlS[4096];

    const int tid  = threadIdx.x;
    const int lane = tid & 63;
    const int wid  = tid >> 6;      // 0..3
    const int wm   = wid >> 1;      // wave row (0..1)
    const int wn   = wid & 1;       // wave col (0..1)
    const int bm = blockIdx.y * 128;
    const int bn = blockIdx.x * 128;

    f32x4 acc[4][4];
#pragma unroll
    for (int i = 0; i < 4; ++i)
#pragma unroll
        for (int j = 0; j < 4; ++j) acc[i][j] = (f32x4){0.f, 0.f, 0.f, 0.f};

    const int ksteps = (K + BK - 1) / BK;
    for (int ks = 0; ks < ksteps; ++ks) {
        const int k0 = ks * BK;
        const bool fullk = (k0 + BK) <= K;

        // ---- stage A-tile: 128 rows x 32 k, split + swizzle to lane order
#pragma unroll
        for (int i = 0; i < 4; ++i) {
            int idx = i * 256 + tid;        // 0..1023
            int m  = idx >> 3;              // 0..127
            int kq = idx & 7;               // float4 index along k
            int kl = kq * 4;
            const float* ap = A + (size_t)(bm + m) * lda + (k0 + kl);
            float v0, v1, v2, v3;
            if (fullk) {
                float4 t = *(const float4*)ap;
                v0 = t.x; v1 = t.y; v2 = t.z; v3 = t.w;
            } else {
                v0 = (k0 + kl + 0 < K) ? ap[0] : 0.f;
                v1 = (k0 + kl + 1 < K) ? ap[1] : 0.f;
                v2 = (k0 + kl + 2 < K) ? ap[2] : 0.f;
                v3 = (k0 + kl + 3 < K) ? ap[3] : 0.f;
            }
            short4 hv, lv;
            hv.x = f2bf(v0); lv.x = f2bf(v0 - bf2f(hv.x));
            hv.y = f2bf(v1); lv.y = f2bf(v1 - bf2f(hv.y));
            hv.z = f2bf(v2); lv.z = f2bf(v2 - bf2f(hv.z));
            hv.w = f2bf(v3); lv.w = f2bf(v3 - bf2f(hv.w));
            int lanei = (m & 15) + 16 * (kq >> 1);          // quad = kq>>1
            int off = (((m >> 4) * 64 + lanei) << 3) + (kq & 1) * 4;
            *(short4*)&AhS[off] = hv;
            *(short4*)&AlS[off] = lv;
        }
        // ---- stage B-tile: 32 k x 128 n, split + swizzle (scattered b16)
#pragma unroll
        for (int i = 0; i < 4; ++i) {
            int idx = i * 256 + tid;        // 0..1023
            int kl = idx >> 5;              // 0..31
            int n  = (idx & 31) * 4;
            int gn = bn + n;
            bool krow = (k0 + kl) < K;
            const float* wp = W + (size_t)(k0 + kl) * N + gn;
            float v[4];
            if (krow && (gn + 3 < N)) {
                float4 t = *(const float4*)wp;
                v[0] = t.x; v[1] = t.y; v[2] = t.z; v[3] = t.w;
            } else {
                v[0] = (krow && gn + 0 < N) ? wp[0] : 0.f;
                v[1] = (krow && gn + 1 < N) ? wp[1] : 0.f;
                v[2] = (krow && gn + 2 < N) ? wp[2] : 0.f;
                v[3] = (krow && gn + 3 < N) ? wp[3] : 0.f;
            }
            int lanebase = 16 * (kl >> 3);
            int j = kl & 7;
#pragma unroll
            for (int e = 0; e < 4; ++e) {
                short h = f2bf(v[e]);
                short l = f2bf(v[e] - bf2f(h));
                int ne = n + e;
                int off = ((((ne >> 4) * 64) + (ne & 15) + lanebase) << 3) + j;
                BhS[off] = h;
                BlS[off] = l;
            }
        }
        __syncthreads();

        // ---- MFMA: 3 products per (im,in) tile pair
        bf16x8 ah[4], al[4], bh[4], bl[4];
#pragma unroll
        for (int t = 0; t < 4; ++t) {
            int ai = ((wm * 4 + t) * 64 + lane) << 3;
            ah[t] = *(const bf16x8*)&AhS[ai];
            al[t] = *(const bf16x8*)&AlS[ai];
            int bi = ((wn * 4 + t) * 64 + lane) << 3;
            bh[t] = *(const bf16x8*)&BhS[bi];
            bl[t] = *(const bf16x8*)&BlS[bi];
        }
#pragma unroll
        for (int im = 0; im < 4; ++im)
#pragma unroll
            for (int in = 0; in < 4; ++in) {
                acc[im][in] = __builtin_amdgcn_mfma_f32_16x16x32_bf16(ah[im], bh[in], acc[im][in], 0, 0, 0);
                acc[im][in] = __builtin_amdgcn_mfma_f32_16x16x32_bf16(ah[im], bl[in], acc[im][in], 0, 0, 0);
                acc[im][in] = __builtin_amdgcn_mfma_f32_16x16x32_bf16(al[im], bh[in], acc[im][in], 0, 0, 0);
            }
        __syncthreads();
    }

    // ---- epilogue: D layout col=lane&15, row=quad*4+reg
    const int qrow = (lane >> 4) * 4;
#pragma unroll
    for (int im = 0; im < 4; ++im) {
        int rowb = bm + wm * 64 + im * 16 + qrow;
#pragma unroll
        for (int in = 0; in < 4; ++in) {
            int col = bn + wn * 64 + in * 16 + (lane & 15);
            if (col < N) {
#pragma unroll
                for (int r = 0; r < 4; ++r) {
                    size_t cidx = (size_t)(rowb + r) * N + col;
                    float v = acc[im][in][r];
                    if (accflag) v += C[cidx];
                    if (bias) v += bias[col];
                    C[cidx] = apply_act(v, act);
                }
            }
        }
    }
}

// ---------------------------------------------------------------------------
// fp32 scalar GEMM kept for the router projection (selection-critical path).
template <int ID>
__global__ __launch_bounds__(256, 2) void gemm_kernel(
    const float* __restrict__ A, int lda,
    const float* __restrict__ W,
    const float* __restrict__ bias,
    float* __restrict__ C,
    int M, int N, int K, int act, int accflag)
{
    __shared__ float As[16][132];
    __shared__ float Bs[16][132];
    const int tid = threadIdx.x;
    const int bm = blockIdx.y * 128;
    const int bn = blockIdx.x * 128;
    const int tx = tid & 15, ty = tid >> 4;

    float acc[8][8];
#pragma unroll
    for (int i = 0; i < 8; ++i)
#pragma unroll
        for (int j = 0; j < 8; ++j) acc[i][j] = 0.f;

    for (int k0 = 0; k0 < K; k0 += 16) {
#pragma unroll
        for (int i = 0; i < 2; ++i) {
            int f = tid + 256 * i;
            int row = f >> 2;
            int kc = (f & 3) * 4;
            const float* ap = A + (size_t)(bm + row) * lda + (k0 + kc);
            float4 v = *(const float4*)ap;
            As[kc + 0][row] = v.x; As[kc + 1][row] = v.y;
            As[kc + 2][row] = v.z; As[kc + 3][row] = v.w;
        }
#pragma unroll
        for (int i = 0; i < 2; ++i) {
            int f = tid + 256 * i;
            int row = f >> 5;
            int col = (f & 31) * 4;
            int gn = bn + col;
            const float* wp = W + (size_t)(k0 + row) * N + gn;
            float4 v;
            if (gn + 3 < N) v = *(const float4*)wp;
            else {
                v.x = (gn + 0 < N) ? wp[0] : 0.f;
                v.y = (gn + 1 < N) ? wp[1] : 0.f;
                v.z = (gn + 2 < N) ? wp[2] : 0.f;
                v.w = (gn + 3 < N) ? wp[3] : 0.f;
            }
            *(float4*)&Bs[row][col] = v;
        }
        __syncthreads();
#pragma unroll
        for (int kk = 0; kk < 16; ++kk) {
            float a[8], b[8];
            *(float4*)&a[0] = *(const float4*)&As[kk][ty * 4];
            *(float4*)&a[4] = *(const float4*)&As[kk][64 + ty * 4];
            *(float4*)&b[0] = *(const float4*)&Bs[kk][tx * 4];
            *(float4*)&b[4] = *(const float4*)&Bs[kk][64 + tx * 4];
#pragma unroll
            for (int i = 0; i < 8; ++i)
#pragma unroll
                for (int j = 0; j < 8; ++j)
                    acc[i][j] = fmaf(a[i], b[j], acc[i][j]);
        }
        __syncthreads();
    }

#pragma unroll
    for (int ii = 0; ii < 8; ++ii) {
        int row = bm + ((ii < 4) ? (ty * 4 + ii) : (64 + ty * 4 + ii - 4));
#pragma unroll
        for (int jj = 0; jj < 8; ++jj) {
            int col = bn + ((jj < 4) ? (tx * 4 + jj) : (64 + tx * 4 + jj - 4));
            if (col < N) {
                size_t cidx = (size_t)row * N + col;
                float v = acc[ii][jj];
                if (accflag) v += C[cidx];
                if (bias) v += bias[col];
                C[cidx] = apply_act(v, act);
            }
        }
    }
}

// ---------------------------------------------------------------------------
__global__ __launch_bounds__(256) void ln_kernel(
    const float* __restrict__ x, const float* __restrict__ w,
    const float* __restrict__ b, float* __restrict__ out)
{
    const int row = blockIdx.x, tid = threadIdx.x;
    const float* xp = x + (size_t)row * Dm;
    float v0 = xp[tid], v1 = xp[tid + 256], v2 = xp[tid + 512];
    float s1 = v0 + v1 + v2;
    float s2 = v0 * v0 + v1 * v1 + v2 * v2;
#pragma unroll
    for (int off = 32; off; off >>= 1) {
        s1 += __shfl_down(s1, off, 64);
        s2 += __shfl_down(s2, off, 64);
    }
    __shared__ float r1[4], r2[4];
    int wid = tid >> 6, lane = tid & 63;
    if (lane == 0) { r1[wid] = s1; r2[wid] = s2; }
    __syncthreads();
    s1 = r1[0] + r1[1] + r1[2] + r1[3];
    s2 = r2[0] + r2[1] + r2[2] + r2[3];
    float mu = s1 * (1.f / 768.f);
    float var = s2 * (1.f / 768.f) - mu * mu;
    float rstd = rsqrtf(var + 1e-5f);
    float* op = out + (size_t)row * Dm;
    op[tid]       = (v0 - mu) * rstd * w[tid]       + b[tid];
    op[tid + 256] = (v1 - mu) * rstd * w[tid + 256] + b[tid + 256];
    op[tid + 512] = (v2 - mu) * rstd * w[tid + 512] + b[tid + 512];
}

// ---------------------------------------------------------------------------
__global__ __launch_bounds__(256) void rope_kernel(float* __restrict__ qkv)
{
    int id = blockIdx.x * 256 + threadIdx.x;   // B*S*H*32
    int i = id & 31;
    int h = (id >> 5) % Hc;
    int r = id / (32 * Hc);        // b*S + s
    int s = r & (Sc - 1);
    float inv = powf(10000.f, -(float)(2 * i) * (1.f / 64.f));
    float f = (float)s * inv;
    float sn, cs;
    sincosf(f, &sn, &cs);
    float* base = qkv + (size_t)r * 2304 + h * 64 + i;
    float q1 = base[0], q2 = base[32];
    base[0]  = q1 * cs - q2 * sn;
    base[32] = q1 * sn + q2 * cs;
    float* kb = base + Dm;
    float k1 = kb[0], k2 = kb[32];
    kb[0]  = k1 * cs - k2 * sn;
    kb[32] = k1 * sn + k2 * cs;
}

// ---------------------------------------------------------------------------
// Flash-attention partial over a 512-key chunk (unchanged, verified).
__global__ __launch_bounds__(256) void attn_partial_kernel(
    const float* __restrict__ qkv, float* __restrict__ po,
    float* __restrict__ pm, float* __restrict__ pl)
{
    __shared__ float Kt[64][64];
    __shared__ float Vt[64][64];
    const int tid = threadIdx.x;
    const int bh = blockIdx.y;              // 0..23
    const int b = bh / Hc, h = bh % Hc;
    const int chunk = blockIdx.z;           // 0..3
    const int u = tid & 1;
    const int pr = tid >> 1;                // 0..127
    const int sA = blockIdx.x * 256 + 2 * pr;

    float qA[32], qB[32], oA[32], oB[32];
    {
        const float* qpA = qkv + ((size_t)(b * Sc + sA)) * 2304 + h * 64 + 32 * u;
        const float* qpB = qpA + 2304;
#pragma unroll
        for (int i = 0; i < 8; ++i) {
            float4 a = *(const float4*)(qpA + 4 * i);
            float4 bb = *(const float4*)(qpB + 4 * i);
            qA[4*i+0] = a.x * 0.125f; qA[4*i+1] = a.y * 0.125f;
            qA[4*i+2] = a.z * 0.125f; qA[4*i+3] = a.w * 0.125f;
            qB[4*i+0] = bb.x * 0.125f; qB[4*i+1] = bb.y * 0.125f;
            qB[4*i+2] = bb.z * 0.125f; qB[4*i+3] = bb.w * 0.125f;
        }
    }
#pragma unroll
    for (int i = 0; i < 32; ++i) { oA[i] = 0.f; oB[i] = 0.f; }
    float mA = -1e30f, lA = 0.f, mB = -1e30f, lB = 0.f;

    const int k0base = chunk * 512;
    for (int kt = 0; kt < 512; kt += 64) {
#pragma unroll
        for (int i = 0; i < 8; ++i) {
            int f = tid + 256 * i;          // 0..2047
            int isV = f >> 10;              // 0:K 1:V
            int g = f & 1023;
            int row = g >> 4;
            int c4 = (g & 15) * 4;
            const float* src = qkv + ((size_t)(b * Sc + k0base + kt + row)) * 2304
                             + Dm + isV * Dm + h * 64 + c4;
            if (isV) *(float4*)&Vt[row][c4] = *(const float4*)src;
            else     *(float4*)&Kt[row][c4] = *(const float4*)src;
        }
        __syncthreads();

#pragma unroll 1
        for (int j0 = 0; j0 < 64; j0 += 8) {
            float pa[8], pb[8];
#pragma unroll
            for (int jj = 0; jj < 8; ++jj) {
                const float* kr = &Kt[j0 + jj][32 * u];
                float da0 = 0.f, da1 = 0.f, db0 = 0.f, db1 = 0.f;
#pragma unroll
                for (int c = 0; c < 4; ++c) {
                    float4 k1v = *(const float4*)(kr + 8 * c);
                    float4 k2v = *(const float4*)(kr + 8 * c + 4);
                    da0 += qA[8*c+0]*k1v.x + qA[8*c+1]*k1v.y + qA[8*c+2]*k1v.z + qA[8*c+3]*k1v.w;
                    da1 += qA[8*c+4]*k2v.x + qA[8*c+5]*k2v.y + qA[8*c+6]*k2v.z + qA[8*c+7]*k2v.w;
                    db0 += qB[8*c+0]*k1v.x + qB[8*c+1]*k1v.y + qB[8*c+2]*k1v.z + qB[8*c+3]*k1v.w;
                    db1 += qB[8*c+4]*k2v.x + qB[8*c+5]*k2v.y + qB[8*c+6]*k2v.z + qB[8*c+7]*k2v.w;
                }
                float da = da0 + da1;
                float db = db0 + db1;
                da += __shfl_xor(da, 1, 64);
                db += __shfl_xor(db, 1, 64);
                pa[jj] = da; pb[jj] = db;
            }
            float cmA = pa[0], cmB = pb[0];
#pragma unroll
            for (int jj = 1; jj < 8; ++jj) {
                cmA = fmaxf(cmA, pa[jj]); cmB = fmaxf(cmB, pb[jj]);
            }
            float nmA = fmaxf(mA, cmA), nmB = fmaxf(mB, cmB);
            float sfA = __expf(mA - nmA), sfB = __expf(mB - nmB);
            mA = nmA; mB = nmB;
            lA *= sfA; lB *= sfB;
#pragma unroll
            for (int i = 0; i < 32; ++i) { oA[i] *= sfA; oB[i] *= sfB; }
#pragma unroll
            for (int jj = 0; jj < 8; ++jj) {
                pa[jj] = __expf(pa[jj] - mA); lA += pa[jj];
                pb[jj] = __expf(pb[jj] - mB); lB += pb[jj];
            }
#pragma unroll
            for (int jj = 0; jj < 8; ++jj) {
                const float* vr = &Vt[j0 + jj][32 * u];
                float paj = pa[jj], pbj = pb[jj];
#pragma unroll
                for (int c = 0; c < 8; ++c) {
                    float4 vv = *(const float4*)(vr + 4 * c);
                    oA[4*c+0] += paj * vv.x; oA[4*c+1] += paj * vv.y;
                    oA[4*c+2] += paj * vv.z; oA[4*c+3] += paj * vv.w;
                    oB[4*c+0] += pbj * vv.x; oB[4*c+1] += pbj * vv.y;
                    oB[4*c+2] += pbj * vv.z; oB[4*c+3] += pbj * vv.w;
                }
            }
        }
        __syncthreads();
    }

    const size_t qiA = (size_t)bh * Sc + sA;
    const size_t qiB = qiA + 1;
    float* poA = po + ((size_t)chunk * NQ + qiA) * 64 + 32 * u;
    float* poB = po + ((size_t)chunk * NQ + qiB) * 64 + 32 * u;
#pragma unroll
    for (int i = 0; i < 8; ++i) {
        float4 t;
        t.x = oA[4*i+0]; t.y = oA[4*i+1]; t.z = oA[4*i+2]; t.w = oA[4*i+3];
        *(float4*)(poA + 4 * i) = t;
        t.x = oB[4*i+0]; t.y = oB[4*i+1]; t.z = oB[4*i+2]; t.w = oB[4*i+3];
        *(float4*)(poB + 4 * i) = t;
    }
    if (u == 0) {
        pm[(size_t)chunk * NQ + qiA] = mA;
        pl[(size_t)chunk * NQ + qiA] = lA;
        pm[(size_t)chunk * NQ + qiB] = mB;
        pl[(size_t)chunk * NQ + qiB] = lB;
    }
}

// Merge NCH partials -> ao (B,S,Dm). Block = 4 queries x 64 dims.
__global__ __launch_bounds__(256) void attn_combine_kernel(
    const float* __restrict__ po, const float* __restrict__ pm,
    const float* __restrict__ pl, float* __restrict__ ao)
{
    const int tid = threadIdx.x;
    const int d = tid & 63;
    const int qi = blockIdx.x * 4 + (tid >> 6);   // bh*Sc + s
    const int bh = qi >> 11;
    const int s = qi & (Sc - 1);
    const int b = bh / Hc, h = bh % Hc;
    float m0 = pm[qi], m1 = pm[NQ + qi], m2 = pm[2*NQ + qi], m3 = pm[3*NQ + qi];
    float M = fmaxf(fmaxf(m0, m1), fmaxf(m2, m3));
    float w0 = __expf(m0 - M), w1 = __expf(m1 - M);
    float w2 = __expf(m2 - M), w3 = __expf(m3 - M);
    float l = w0 * pl[qi] + w1 * pl[NQ + qi] + w2 * pl[2*NQ + qi] + w3 * pl[3*NQ + qi];
    float o = w0 * po[(size_t)qi * 64 + d]
            + w1 * po[((size_t)NQ + qi) * 64 + d]
            + w2 * po[((size_t)2*NQ + qi) * 64 + d]
            + w3 * po[((size_t)3*NQ + qi) * 64 + d];
    ao[((size_t)(b * Sc + s)) * Dm + h * 64 + d] = o / l;
}

// ---------------------------------------------------------------------------
__global__ __launch_bounds__(256) void conv_silu_kernel(
    const float* __restrict__ xz, const float* __restrict__ cw,
    const float* __restrict__ cb, float* __restrict__ u)
{
    int id = blockIdx.x * 256 + threadIdx.x;   // B*S*DI
    int d = id % DI;
    int r = id / DI;
    int s = r & (Sc - 1);
    int b = r >> 11;
    float acc = cb[d];
#pragma unroll
    for (int j = 0; j < 4; ++j) {
        int sp = s + j - 3;
        if (sp >= 0)
            acc += xz[((size_t)(b * Sc + sp)) * (2 * DI) + d] * cw[d * 4 + j];
    }
    u[id] = acc / (1.f + __expf(-acc));
}

// ---------------------------------------------------------------------------
__global__ __launch_bounds__(256) void scan_kernel(
    const float* __restrict__ delta, const float* __restrict__ u,
    const float* __restrict__ dbc, const float* __restrict__ A_log,
    const float* __restrict__ Dp, float* __restrict__ y)
{
    int gid = blockIdx.x * 256 + threadIdx.x;
    int n = gid & 15;
    int ch = gid >> 4;
    int b = ch / DI;
    int dd = ch - b * DI;
    float Av = -__expf(A_log[dd * NST + n]);
    float Dv = Dp[dd];
    const float* dp = delta + (size_t)b * Sc * DI + dd;
    const float* up = u     + (size_t)b * Sc * DI + dd;
    const float* Bp = dbc   + (size_t)b * Sc * 80 + DTR + n;
    const float* Cp = Bp + NST;
    float* yp = y + (size_t)b * Sc * DI + dd;

    float h = 0.f;
    constexpr int CH = 8;
    float cdt[CH], cu[CH], cB[CH], cC[CH];
    float ndt[CH], nu[CH], nB[CH], nC[CH];
#pragma unroll
    for (int i = 0; i < CH; ++i) {
        cdt[i] = dp[(size_t)i * DI]; cu[i] = up[(size_t)i * DI];
        cB[i] = Bp[(size_t)i * 80];  cC[i] = Cp[(size_t)i * 80];
    }
    for (int t0 = 0; t0 < Sc; t0 += CH) {
        bool more = (t0 + CH < Sc);
        if (more) {
#pragma unroll
            for (int i = 0; i < CH; ++i) {
                size_t t = t0 + CH + i;
                ndt[i] = dp[t * DI]; nu[i] = up[t * DI];
                nB[i] = Bp[t * 80];  nC[i] = Cp[t * 80];
            }
        }
#pragma unroll
        for (int i = 0; i < CH; ++i) {
            float dt = cdt[i];
            h = __expf(dt * Av) * h + dt * cu[i] * cB[i];
            float p = h * cC[i];
            p += __shfl_xor(p, 1, 16);
            p += __shfl_xor(p, 2, 16);
            p += __shfl_xor(p, 4, 16);
            p += __shfl_xor(p, 8, 16);
            if (n == 0) yp[(size_t)(t0 + i) * DI] = p + cu[i] * Dv;
        }
        if (more) {
#pragma unroll
            for (int i = 0; i < CH; ++i) {
                cdt[i] = ndt[i]; cu[i] = nu[i]; cB[i] = nB[i]; cC[i] = nC[i];
            }
        }
    }
}

// ---------------------------------------------------------------------------
__global__ __launch_bounds__(256) void ssmin_kernel(
    float* __restrict__ y, const float* __restrict__ xz)
{
    int id = blockIdx.x * 256 + threadIdx.x;
    int d = id % DI;
    int r = id / DI;
    float z = xz[(size_t)r * (2 * DI) + DI + d];
    y[id] = y[id] * (z / (1.f + __expf(-z)));
}

// ---------------------------------------------------------------------------
__global__ __launch_bounds__(256) void x1_kernel(
    const float* __restrict__ x, const float* __restrict__ g,
    const float* __restrict__ at, const float* __restrict__ sm,
    float* __restrict__ x1)
{
    int id = blockIdx.x * 256 + threadIdx.x;
    float gv = g[id];
    x1[id] = x[id] + gv * at[id] + (1.f - gv) * sm[id];
}

// ---------------------------------------------------------------------------
__global__ __launch_bounds__(256) void rowdot_kernel(
    const float* __restrict__ rh, const float* __restrict__ w2,
    const float* __restrict__ b2, float* __restrict__ sc)
{
    int lane = threadIdx.x & 63;
    int t = blockIdx.x * 4 + (threadIdx.x >> 6);
    const float* rp = rh + (size_t)t * 192;
    float sum = rp[lane] * w2[lane] + rp[lane + 64] * w2[lane + 64]
              + rp[lane + 128] * w2[lane + 128];
#pragma unroll
    for (int off = 32; off; off >>= 1) sum += __shfl_down(sum, off, 64);
    if (lane == 0) sc[t] = sum + b2[0];
}

// ---------------------------------------------------------------------------
__global__ __launch_bounds__(256) void topk_kernel(
    const float* __restrict__ sc, int* __restrict__ idxb)
{
    __shared__ float vals[Sc];
    __shared__ float rv[4];
    __shared__ int ri[4];
    const int b = blockIdx.x, tid = threadIdx.x;
    for (int i = tid; i < Sc; i += 256) vals[i] = sc[(size_t)b * Sc + i];
    __syncthreads();
    for (int it = 0; it < CAP; ++it) {
        float bv = -3.4e38f; int bi = 0x7fffffff;
        for (int i = tid; i < Sc; i += 256) {
            float v = vals[i];
            if (v > bv || (v == bv && i < bi)) { bv = v; bi = i; }
        }
#pragma unroll
        for (int off = 32; off; off >>= 1) {
            float ov = __shfl_down(bv, off, 64);
            int oi = __shfl_down(bi, off, 64);
            if (ov > bv || (ov == bv && oi < bi)) { bv = ov; bi = oi; }
        }
        int lane = tid & 63, wid = tid >> 6;
        if (lane == 0) { rv[wid] = bv; ri[wid] = bi; }
        __syncthreads();
        if (tid == 0) {
            float Bv = rv[0]; int Bi = ri[0];
            for (int w = 1; w < 4; ++w)
                if (rv[w] > Bv || (rv[w] == Bv && ri[w] < Bi)) { Bv = rv[w]; Bi = ri[w]; }
            idxb[b * CAP + it] = Bi;
            vals[Bi] = -3.4e38f;
        }
        __syncthreads();
    }
}

// ---------------------------------------------------------------------------
__global__ __launch_bounds__(256) void gather_kernel(
    const float* __restrict__ xn2, const int* __restrict__ idxb,
    float* __restrict__ Xsel)
{
    int i = blockIdx.x;
    int b = i >> 8;
    int t = idxb[i];
    const float* src = xn2 + ((size_t)(b * Sc + t)) * Dm;
    float* dst = Xsel + (size_t)i * Dm;
    int c = threadIdx.x;
    dst[c] = src[c]; dst[c + 256] = src[c + 256]; dst[c + 512] = src[c + 512];
}

__global__ __launch_bounds__(256) void finaladd_kernel(
    const float* __restrict__ x1, const float* __restrict__ xn2,
    float* __restrict__ out)
{
    int id = blockIdx.x * 256 + threadIdx.x;
    out[id] = x1[id] + xn2[id];
}

__global__ __launch_bounds__(256) void scatter_kernel(
    const float* __restrict__ x1, const float* __restrict__ proc,
    const int* __restrict__ idxb, float* __restrict__ out)
{
    int i = blockIdx.x;
    int b = i >> 8;
    int t = idxb[i];
    size_t ro = ((size_t)(b * Sc + t)) * Dm;
    const float* pp = proc + (size_t)i * Dm;
    int c = threadIdx.x;
    out[ro + c]       = x1[ro + c]       + pp[c];
    out[ro + c + 256] = x1[ro + c + 256] + pp[c + 256];
    out[ro + c + 512] = x1[ro + c + 512] + pp[c + 512];
}

// ---------------------------------------------------------------------------
extern "C" void kernel_launch(void* const* d_in, const int* in_sizes, int n_in,
                              void* d_out, int out_size, void* d_ws, size_t ws_size,
                              hipStream_t stream)
{
    (void)in_sizes; (void)n_in; (void)out_size; (void)ws_size;
    const float* x          = (const float*)d_in[0];
    const float* ln1_w      = (const float*)d_in[1];
    const float* ln1_b      = (const float*)d_in[2];
    const float* ln2_w      = (const float*)d_in[3];
    const float* ln2_b      = (const float*)d_in[4];
    const float* qkv_w      = (const float*)d_in[5];
    const float* attn_out_w = (const float*)d_in[6];
    const float* attn_out_b = (const float*)d_in[7];
    const float* in_proj_w  = (const float*)d_in[8];
    const float* conv_w     = (const float*)d_in[9];
    const float* conv_b     = (const float*)d_in[10];
    const float* x_proj_w   = (const float*)d_in[11];
    const float* dt_w       = (const float*)d_in[12];
    const float* dt_b       = (const float*)d_in[13];
    const float* A_log      = (const float*)d_in[14];
    const float* Dvec       = (const float*)d_in[15];
    const float* ssm_out_w  = (const float*)d_in[16];
    const float* gate_w     = (const float*)d_in[17];
    const float* gate_b     = (const float*)d_in[18];
    const float* ffn_w1     = (const float*)d_in[19];
    const float* ffn_b1     = (const float*)d_in[20];
    const float* ffn_w2     = (const float*)d_in[21];
    const float* ffn_b2     = (const float*)d_in[22];
    const float* r_w1       = (const float*)d_in[23];
    const float* r_b1       = (const float*)d_in[24];
    const float* r_w2       = (const float*)d_in[25];
    const float* r_b2       = (const float*)d_in[26];
    float* out = (float*)d_out;

    float* ws = (float*)d_ws;
    const size_t TOK = (size_t)M_ * Dm;
    float* xn   = ws;
    float* ao   = xn + TOK;
    float* y    = xn;                         // alias (scan output spans xn+ao)
    float* qkv  = ao + TOK;
    float* delta = qkv;                       // alias (after attention consumes qkv)
    float* xz   = qkv + (size_t)M_ * 2304;
    float* u    = xz + (size_t)M_ * 2 * DI;
    float* dbc  = u + (size_t)M_ * DI;
    float* attn_out = dbc + (size_t)M_ * 80;
    float* ssm_out  = attn_out + TOK;
    float* g    = ssm_out + TOK;
    float* x1   = g + TOK;
    float* xn2  = x1 + TOK;
    float* rh   = xn2 + TOK;
    float* sc   = rh + (size_t)M_ * 192;
    int*   idxb = (int*)(sc + M_);
    float* Xsel = sc + M_ + 512;
    float* Hsel = Xsel + (size_t)512 * Dm;
    float* proc = Hsel + (size_t)512 * DF;

    // Attention partial buffers (arenas dead until combine consumes them)
    float* po  = attn_out;
    float* pmb = rh;
    float* plb = rh + (size_t)NCH * NQ;

    // 1. LN1
    ln_kernel<<<M_, 256, 0, stream>>>(x, ln1_w, ln1_b, xn);
    // 2. QKV projection
    gemm_mfma<0><<<dim3(18, 32), 256, 0, stream>>>(xn, Dm, qkv_w, nullptr, qkv, M_, 2304, 768, 0, 0);
    // 3. RoPE
    rope_kernel<<<(Bc * Sc * Hc * 32) / 256, 256, 0, stream>>>(qkv);
    // 4. Attention: key-split partials + combine
    attn_partial_kernel<<<dim3(Sc / 256, Bc * Hc, NCH), 256, 0, stream>>>(qkv, po, pmb, plb);
    attn_combine_kernel<<<NQ / 4, 256, 0, stream>>>(po, pmb, plb, ao);
    // 5. attn_out projection
    gemm_mfma<1><<<dim3(6, 32), 256, 0, stream>>>(ao, Dm, attn_out_w, attn_out_b, attn_out, M_, 768, 768, 0, 0);
    // 6. in_proj
    gemm_mfma<2><<<dim3(24, 32), 256, 0, stream>>>(xn, Dm, in_proj_w, nullptr, xz, M_, 2 * DI, 768, 0, 0);
    // 7. causal conv + SiLU
    conv_silu_kernel<<<(M_ * DI) / 256, 256, 0, stream>>>(xz, conv_w, conv_b, u);
    // 8. x_proj (N=80 ragged)
    gemm_mfma<3><<<dim3(1, 32), 256, 0, stream>>>(u, DI, x_proj_w, nullptr, dbc, M_, 80, 1536, 0, 0);
    // 9. delta (K=48 tail)
    gemm_mfma<4><<<dim3(12, 32), 256, 0, stream>>>(dbc, 80, dt_w, dt_b, delta, M_, DI, DTR, 1, 0);
    // 10. scan
    scan_kernel<<<(Bc * DI * NST) / 256, 256, 0, stream>>>(delta, u, dbc, A_log, Dvec, y);
    // 11. y *= silu(z)
    ssmin_kernel<<<(M_ * DI) / 256, 256, 0, stream>>>(y, xz);
    // 12. ssm_out
    gemm_mfma<5><<<dim3(6, 32), 256, 0, stream>>>(y, DI, ssm_out_w, nullptr, ssm_out, M_, 768, 1536, 0, 0);
    // 13/14. gate
    gemm_mfma<6><<<dim3(6, 32), 256, 0, stream>>>(attn_out, Dm, gate_w, nullptr, g, M_, 768, 768, 0, 0);
    gemm_mfma<7><<<dim3(6, 32), 256, 0, stream>>>(ssm_out, Dm, gate_w + (size_t)768 * 768, gate_b, g, M_, 768, 768, 2, 1);
    // 15. x1
    x1_kernel<<<(M_ * Dm) / 256, 256, 0, stream>>>(x, g, attn_out, ssm_out, x1);
    // 16. LN2
    ln_kernel<<<M_, 256, 0, stream>>>(x1, ln2_w, ln2_b, xn2);
    // 17. router hidden — kept pure fp32 (selection-critical)
    gemm_kernel<8><<<dim3(2, 32), 256, 0, stream>>>(xn2, Dm, r_w1, r_b1, rh, M_, 192, 768, 3, 0);
    // 18. scores
    rowdot_kernel<<<M_ / 4, 256, 0, stream>>>(rh, r_w2, r_b2, sc);
    // 19. top-k
    topk_kernel<<<Bc, 256, 0, stream>>>(sc, idxb);
    // 20. gather
    gather_kernel<<<Bc * CAP, 256, 0, stream>>>(xn2, idxb, Xsel);
    // 21. FFN1
    gemm_mfma<9><<<dim3(24, 4), 256, 0, stream>>>(Xsel, Dm, ffn_w1, ffn_b1, Hsel, Bc * CAP, DF, 768, 4, 0);
    // 22. FFN2
    gemm_mfma<10><<<dim3(6, 4), 256, 0, stream>>>(Hsel, DF, ffn_w2, ffn_b2, proc, Bc * CAP, 768, DF, 0, 0);
    // 23. out = x1 + xn2
    finaladd_kernel<<<(M_ * Dm) / 256, 256, 0, stream>>>(x1, xn2, out);
    // 24. scatter
    scatter_kernel<<<Bc * CAP, 256, 0, stream>>>(x1, proc, idxb, out);
}

// Round 9
// 2920.752 us; speedup vs baseline: 1.4666x; 1.3420x over previous
//
#include <hip/hip_runtime.h>
#include <cstdint>
#include <cstddef>

// Problem constants
constexpr int Bc   = 2;
constexpr int Sc   = 2048;
constexpr int Dm   = 768;
constexpr int Hc   = 12;
constexpr int DI   = 1536;
constexpr int NST  = 16;
constexpr int DTR  = 48;
constexpr int CAP  = 256;
constexpr int DF   = 3072;
constexpr int M_   = Bc * Sc;        // 4096
constexpr int NQ   = Bc * Hc * Sc;   // 49152
constexpr int NCH  = 4;
constexpr size_t TOK = (size_t)M_ * Dm;   // 3,145,728

typedef __attribute__((ext_vector_type(8))) short bf16x8;
typedef __attribute__((ext_vector_type(4))) float f32x4;

__device__ __forceinline__ float apply_act(float v, int act) {
    switch (act) {
        case 1: return (v > 20.f) ? v : log1pf(__expf(v));
        case 2: return 1.f / (1.f + __expf(-v));
        case 3: return fmaxf(v, 0.f);
        case 4: return 0.5f * v * (1.f + erff(v * 0.70710678118654752f));
        default: return v;
    }
}
__device__ __forceinline__ short f2bf(float x) {   // RNE
    unsigned u = __float_as_uint(x);
    unsigned r = u + 0x7FFFu + ((u >> 16) & 1u);
    return (short)(r >> 16);
}
__device__ __forceinline__ float bf2f(short h) {
    return __uint_as_float(((unsigned)(unsigned short)h) << 16);
}

// ---------------------------------------------------------------------------
// Weight pre-swizzle: fp32 [K x N] -> bf16 hi/lo in MFMA B-fragment order.
// fragment(ks,nt) at (ks*NT+nt)*512; within: lane=(kq*16+(n&15)), elem j=k&7.
__global__ __launch_bounds__(256) void wswz_kernel(
    const float* __restrict__ W, short* __restrict__ Wh, short* __restrict__ Wl,
    int K, int N, int Kpad, int Npad)
{
    int id = blockIdx.x * 256 + threadIdx.x;
    if (id >= Kpad * Npad) return;
    int n = id % Npad, k = id / Npad;
    float v = (k < K && n < N) ? W[(size_t)k * N + n] : 0.f;
    short h = f2bf(v);
    short l = f2bf(v - bf2f(h));
    int NT = Npad >> 4;
    size_t off = ((((size_t)(k >> 5) * NT + (n >> 4)) * 4 + ((k >> 3) & 3)) * 16
                  + (n & 15)) * 8 + (k & 7);
    Wh[off] = h; Wl[off] = l;
}

// ---------------------------------------------------------------------------
// bf16x3 MFMA GEMM: fp32 A (row-major, lda), pre-swizzled bf16 B hi/lo.
// C = act(acc*C + A@W + bias). Tile 128x128x32, 4 waves of 64x64.
// A split to hi/lo in-kernel during LDS staging (RNE both, r6 numerics).
// B fragments loaded directly global->VGPR. M%128==0; K arbitrary (zero-fill
// chunks past K; B swizzle zero-padded to Kpad/Npad). ntiles = Npad/16.
template <int ID>
__global__ __launch_bounds__(256, 2) void gemm_bf3(
    const float* __restrict__ A, int lda,
    const short* __restrict__ Bh, const short* __restrict__ Bl, int ntiles,
    const float* __restrict__ bias,
    float* __restrict__ C,
    int M, int N, int K, int act, int accflag)
{
    __shared__ __attribute__((aligned(16))) short AhS[4096];
    __shared__ __attribute__((aligned(16))) short AlS[4096];
    const int tid = threadIdx.x, lane = tid & 63, wid = tid >> 6;
    const int wm = wid >> 1, wn = wid & 1;
    const int bm = blockIdx.y * 128, bn = blockIdx.x * 128;

    f32x4 acc[4][4];
#pragma unroll
    for (int i = 0; i < 4; ++i)
#pragma unroll
        for (int j = 0; j < 4; ++j) acc[i][j] = (f32x4){0.f, 0.f, 0.f, 0.f};

    const int ksteps = (K + 31) >> 5;
    for (int ks = 0; ks < ksteps; ++ks) {
        const int k0 = ks << 5;
        // B fragments: direct global loads, contiguous 16B/lane (in flight
        // across the A staging below)
        bf16x8 bh[4], bl[4];
        const size_t bbase = ((size_t)ks * ntiles + (bn >> 4) + wn * 4) * 512
                           + (size_t)lane * 8;
#pragma unroll
        for (int t = 0; t < 4; ++t) {
            bh[t] = *(const bf16x8*)&Bh[bbase + (size_t)t * 512];
            bl[t] = *(const bf16x8*)&Bl[bbase + (size_t)t * 512];
        }
        // A stage: load 8 fp32, RNE-split, store to fragment-order LDS
#pragma unroll
        for (int i = 0; i < 2; ++i) {
            int c = i * 256 + tid;          // chunk 0..511
            int l = c & 63;
            int m = ((c >> 6) << 4) + (l & 15);
            int q = l >> 4;
            int kk = k0 + q * 8;
            short4 h0, l0, h1, l1;
            if (kk + 8 <= K) {
                const float* ap = A + (size_t)(bm + m) * lda + kk;
                float4 f0 = *(const float4*)ap;
                float4 f1 = *(const float4*)(ap + 4);
                h0.x = f2bf(f0.x); l0.x = f2bf(f0.x - bf2f(h0.x));
                h0.y = f2bf(f0.y); l0.y = f2bf(f0.y - bf2f(h0.y));
                h0.z = f2bf(f0.z); l0.z = f2bf(f0.z - bf2f(h0.z));
                h0.w = f2bf(f0.w); l0.w = f2bf(f0.w - bf2f(h0.w));
                h1.x = f2bf(f1.x); l1.x = f2bf(f1.x - bf2f(h1.x));
                h1.y = f2bf(f1.y); l1.y = f2bf(f1.y - bf2f(h1.y));
                h1.z = f2bf(f1.z); l1.z = f2bf(f1.z - bf2f(h1.z));
                h1.w = f2bf(f1.w); l1.w = f2bf(f1.w - bf2f(h1.w));
            } else {
                h0 = short4{0,0,0,0}; l0 = h0; h1 = h0; l1 = h0;
            }
            int off = c * 8;
            *(short4*)&AhS[off]     = h0;
            *(short4*)&AhS[off + 4] = h1;
            *(short4*)&AlS[off]     = l0;
            *(short4*)&AlS[off + 4] = l1;
        }
        __syncthreads();
        bf16x8 ah[4], al[4];
#pragma unroll
        for (int t = 0; t < 4; ++t) {
            int ai = ((wm * 4 + t) * 64 + lane) * 8;
            ah[t] = *(const bf16x8*)&AhS[ai];
            al[t] = *(const bf16x8*)&AlS[ai];
        }
#pragma unroll
        for (int im = 0; im < 4; ++im)
#pragma unroll
            for (int in = 0; in < 4; ++in) {
                acc[im][in] = __builtin_amdgcn_mfma_f32_16x16x32_bf16(ah[im], bh[in], acc[im][in], 0, 0, 0);
                acc[im][in] = __builtin_amdgcn_mfma_f32_16x16x32_bf16(ah[im], bl[in], acc[im][in], 0, 0, 0);
                acc[im][in] = __builtin_amdgcn_mfma_f32_16x16x32_bf16(al[im], bh[in], acc[im][in], 0, 0, 0);
            }
        __syncthreads();
    }

    // epilogue: D layout col=lane&15, row=quad*4+reg (r6-verified)
    const int qrow = (lane >> 4) * 4;
#pragma unroll
    for (int im = 0; im < 4; ++im) {
        int rowb = bm + wm * 64 + im * 16 + qrow;
#pragma unroll
        for (int in = 0; in < 4; ++in) {
            int col = bn + wn * 64 + in * 16 + (lane & 15);
            if (col < N) {
#pragma unroll
                for (int r = 0; r < 4; ++r) {
                    size_t cidx = (size_t)(rowb + r) * N + col;
                    float v = acc[im][in][r];
                    if (accflag) v += C[cidx];
                    if (bias) v += bias[col];
                    C[cidx] = apply_act(v, act);
                }
            }
        }
    }
}

// ---------------------------------------------------------------------------
// fp32 scalar GEMM (router projection only — selection-critical).
template <int ID>
__global__ __launch_bounds__(256, 2) void gemm_kernel(
    const float* __restrict__ A, int lda,
    const float* __restrict__ W,
    const float* __restrict__ bias,
    float* __restrict__ C,
    int M, int N, int K, int act, int accflag)
{
    __shared__ float As[16][132];
    __shared__ float Bs[16][132];
    const int tid = threadIdx.x;
    const int bm = blockIdx.y * 128;
    const int bn = blockIdx.x * 128;
    const int tx = tid & 15, ty = tid >> 4;
    float acc[8][8];
#pragma unroll
    for (int i = 0; i < 8; ++i)
#pragma unroll
        for (int j = 0; j < 8; ++j) acc[i][j] = 0.f;
    for (int k0 = 0; k0 < K; k0 += 16) {
#pragma unroll
        for (int i = 0; i < 2; ++i) {
            int f = tid + 256 * i;
            int row = f >> 2;
            int kc = (f & 3) * 4;
            const float* ap = A + (size_t)(bm + row) * lda + (k0 + kc);
            float4 v = *(const float4*)ap;
            As[kc + 0][row] = v.x; As[kc + 1][row] = v.y;
            As[kc + 2][row] = v.z; As[kc + 3][row] = v.w;
        }
#pragma unroll
        for (int i = 0; i < 2; ++i) {
            int f = tid + 256 * i;
            int row = f >> 5;
            int col = (f & 31) * 4;
            int gn = bn + col;
            const float* wp = W + (size_t)(k0 + row) * N + gn;
            float4 v;
            if (gn + 3 < N) v = *(const float4*)wp;
            else {
                v.x = (gn + 0 < N) ? wp[0] : 0.f;
                v.y = (gn + 1 < N) ? wp[1] : 0.f;
                v.z = (gn + 2 < N) ? wp[2] : 0.f;
                v.w = (gn + 3 < N) ? wp[3] : 0.f;
            }
            *(float4*)&Bs[row][col] = v;
        }
        __syncthreads();
#pragma unroll
        for (int kk = 0; kk < 16; ++kk) {
            float a[8], b[8];
            *(float4*)&a[0] = *(const float4*)&As[kk][ty * 4];
            *(float4*)&a[4] = *(const float4*)&As[kk][64 + ty * 4];
            *(float4*)&b[0] = *(const float4*)&Bs[kk][tx * 4];
            *(float4*)&b[4] = *(const float4*)&Bs[kk][64 + tx * 4];
#pragma unroll
            for (int i = 0; i < 8; ++i)
#pragma unroll
                for (int j = 0; j < 8; ++j)
                    acc[i][j] = fmaf(a[i], b[j], acc[i][j]);
        }
        __syncthreads();
    }
#pragma unroll
    for (int ii = 0; ii < 8; ++ii) {
        int row = bm + ((ii < 4) ? (ty * 4 + ii) : (64 + ty * 4 + ii - 4));
#pragma unroll
        for (int jj = 0; jj < 8; ++jj) {
            int col = bn + ((jj < 4) ? (tx * 4 + jj) : (64 + tx * 4 + jj - 4));
            if (col < N) {
                size_t cidx = (size_t)row * N + col;
                float v = acc[ii][jj];
                if (accflag) v += C[cidx];
                if (bias) v += bias[col];
                C[cidx] = apply_act(v, act);
            }
        }
    }
}

// ---------------------------------------------------------------------------
__global__ __launch_bounds__(256) void ln_kernel(
    const float* __restrict__ x, const float* __restrict__ w,
    const float* __restrict__ b, float* __restrict__ out)
{
    const int row = blockIdx.x, tid = threadIdx.x;
    const float* xp = x + (size_t)row * Dm;
    float v0 = xp[tid], v1 = xp[tid + 256], v2 = xp[tid + 512];
    float s1 = v0 + v1 + v2;
    float s2 = v0 * v0 + v1 * v1 + v2 * v2;
#pragma unroll
    for (int off = 32; off; off >>= 1) {
        s1 += __shfl_down(s1, off, 64);
        s2 += __shfl_down(s2, off, 64);
    }
    __shared__ float r1[4], r2[4];
    int wid = tid >> 6, lane = tid & 63;
    if (lane == 0) { r1[wid] = s1; r2[wid] = s2; }
    __syncthreads();
    s1 = r1[0] + r1[1] + r1[2] + r1[3];
    s2 = r2[0] + r2[1] + r2[2] + r2[3];
    float mu = s1 * (1.f / 768.f);
    float var = s2 * (1.f / 768.f) - mu * mu;
    float rstd = rsqrtf(var + 1e-5f);
    float* op = out + (size_t)row * Dm;
    op[tid]       = (v0 - mu) * rstd * w[tid]       + b[tid];
    op[tid + 256] = (v1 - mu) * rstd * w[tid + 256] + b[tid + 256];
    op[tid + 512] = (v2 - mu) * rstd * w[tid + 512] + b[tid + 512];
}

// ---------------------------------------------------------------------------
__global__ __launch_bounds__(256) void rope_kernel(float* __restrict__ qkv)
{
    int id = blockIdx.x * 256 + threadIdx.x;
    int i = id & 31;
    int h = (id >> 5) % Hc;
    int r = id / (32 * Hc);
    int s = r & (Sc - 1);
    float inv = powf(10000.f, -(float)(2 * i) * (1.f / 64.f));
    float f = (float)s * inv;
    float sn, cs;
    sincosf(f, &sn, &cs);
    float* base = qkv + (size_t)r * 2304 + h * 64 + i;
    float q1 = base[0], q2 = base[32];
    base[0]  = q1 * cs - q2 * sn;
    base[32] = q1 * sn + q2 * cs;
    float* kb = base + Dm;
    float k1 = kb[0], k2 = kb[32];
    kb[0]  = k1 * cs - k2 * sn;
    kb[32] = k1 * sn + k2 * cs;
}

// ---------------------------------------------------------------------------
// Flash-attention partial (r6-verified, unchanged)
__global__ __launch_bounds__(256) void attn_partial_kernel(
    const float* __restrict__ qkv, float* __restrict__ po,
    float* __restrict__ pm, float* __restrict__ pl)
{
    __shared__ float Kt[64][64];
    __shared__ float Vt[64][64];
    const int tid = threadIdx.x;
    const int bh = blockIdx.y;
    const int b = bh / Hc, h = bh % Hc;
    const int chunk = blockIdx.z;
    const int u = tid & 1;
    const int pr = tid >> 1;
    const int sA = blockIdx.x * 256 + 2 * pr;

    float qA[32], qB[32], oA[32], oB[32];
    {
        const float* qpA = qkv + ((size_t)(b * Sc + sA)) * 2304 + h * 64 + 32 * u;
        const float* qpB = qpA + 2304;
#pragma unroll
        for (int i = 0; i < 8; ++i) {
            float4 a = *(const float4*)(qpA + 4 * i);
            float4 bb = *(const float4*)(qpB + 4 * i);
            qA[4*i+0] = a.x * 0.125f; qA[4*i+1] = a.y * 0.125f;
            qA[4*i+2] = a.z * 0.125f; qA[4*i+3] = a.w * 0.125f;
            qB[4*i+0] = bb.x * 0.125f; qB[4*i+1] = bb.y * 0.125f;
            qB[4*i+2] = bb.z * 0.125f; qB[4*i+3] = bb.w * 0.125f;
        }
    }
#pragma unroll
    for (int i = 0; i < 32; ++i) { oA[i] = 0.f; oB[i] = 0.f; }
    float mA = -1e30f, lA = 0.f, mB = -1e30f, lB = 0.f;

    const int k0base = chunk * 512;
    for (int kt = 0; kt < 512; kt += 64) {
#pragma unroll
        for (int i = 0; i < 8; ++i) {
            int f = tid + 256 * i;
            int isV = f >> 10;
            int g = f & 1023;
            int row = g >> 4;
            int c4 = (g & 15) * 4;
            const float* src = qkv + ((size_t)(b * Sc + k0base + kt + row)) * 2304
                             + Dm + isV * Dm + h * 64 + c4;
            if (isV) *(float4*)&Vt[row][c4] = *(const float4*)src;
            else     *(float4*)&Kt[row][c4] = *(const float4*)src;
        }
        __syncthreads();
#pragma unroll 1
        for (int j0 = 0; j0 < 64; j0 += 8) {
            float pa[8], pb[8];
#pragma unroll
            for (int jj = 0; jj < 8; ++jj) {
                const float* kr = &Kt[j0 + jj][32 * u];
                float da0 = 0.f, da1 = 0.f, db0 = 0.f, db1 = 0.f;
#pragma unroll
                for (int c = 0; c < 4; ++c) {
                    float4 k1v = *(const float4*)(kr + 8 * c);
                    float4 k2v = *(const float4*)(kr + 8 * c + 4);
                    da0 += qA[8*c+0]*k1v.x + qA[8*c+1]*k1v.y + qA[8*c+2]*k1v.z + qA[8*c+3]*k1v.w;
                    da1 += qA[8*c+4]*k2v.x + qA[8*c+5]*k2v.y + qA[8*c+6]*k2v.z + qA[8*c+7]*k2v.w;
                    db0 += qB[8*c+0]*k1v.x + qB[8*c+1]*k1v.y + qB[8*c+2]*k1v.z + qB[8*c+3]*k1v.w;
                    db1 += qB[8*c+4]*k2v.x + qB[8*c+5]*k2v.y + qB[8*c+6]*k2v.z + qB[8*c+7]*k2v.w;
                }
                float da = da0 + da1;
                float db = db0 + db1;
                da += __shfl_xor(da, 1, 64);
                db += __shfl_xor(db, 1, 64);
                pa[jj] = da; pb[jj] = db;
            }
            float cmA = pa[0], cmB = pb[0];
#pragma unroll
            for (int jj = 1; jj < 8; ++jj) {
                cmA = fmaxf(cmA, pa[jj]); cmB = fmaxf(cmB, pb[jj]);
            }
            float nmA = fmaxf(mA, cmA), nmB = fmaxf(mB, cmB);
            float sfA = __expf(mA - nmA), sfB = __expf(mB - nmB);
            mA = nmA; mB = nmB;
            lA *= sfA; lB *= sfB;
#pragma unroll
            for (int i = 0; i < 32; ++i) { oA[i] *= sfA; oB[i] *= sfB; }
#pragma unroll
            for (int jj = 0; jj < 8; ++jj) {
                pa[jj] = __expf(pa[jj] - mA); lA += pa[jj];
                pb[jj] = __expf(pb[jj] - mB); lB += pb[jj];
            }
#pragma unroll
            for (int jj = 0; jj < 8; ++jj) {
                const float* vr = &Vt[j0 + jj][32 * u];
                float paj = pa[jj], pbj = pb[jj];
#pragma unroll
                for (int c = 0; c < 8; ++c) {
                    float4 vv = *(const float4*)(vr + 4 * c);
                    oA[4*c+0] += paj * vv.x; oA[4*c+1] += paj * vv.y;
                    oA[4*c+2] += paj * vv.z; oA[4*c+3] += paj * vv.w;
                    oB[4*c+0] += pbj * vv.x; oB[4*c+1] += pbj * vv.y;
                    oB[4*c+2] += pbj * vv.z; oB[4*c+3] += pbj * vv.w;
                }
            }
        }
        __syncthreads();
    }

    const size_t qiA = (size_t)bh * Sc + sA;
    const size_t qiB = qiA + 1;
    float* poA = po + ((size_t)chunk * NQ + qiA) * 64 + 32 * u;
    float* poB = po + ((size_t)chunk * NQ + qiB) * 64 + 32 * u;
#pragma unroll
    for (int i = 0; i < 8; ++i) {
        float4 t;
        t.x = oA[4*i+0]; t.y = oA[4*i+1]; t.z = oA[4*i+2]; t.w = oA[4*i+3];
        *(float4*)(poA + 4 * i) = t;
        t.x = oB[4*i+0]; t.y = oB[4*i+1]; t.z = oB[4*i+2]; t.w = oB[4*i+3];
        *(float4*)(poB + 4 * i) = t;
    }
    if (u == 0) {
        pm[(size_t)chunk * NQ + qiA] = mA;
        pl[(size_t)chunk * NQ + qiA] = lA;
        pm[(size_t)chunk * NQ + qiB] = mB;
        pl[(size_t)chunk * NQ + qiB] = lB;
    }
}

__global__ __launch_bounds__(256) void attn_combine_kernel(
    const float* __restrict__ po, const float* __restrict__ pm,
    const float* __restrict__ pl, float* __restrict__ ao)
{
    const int tid = threadIdx.x;
    const int d = tid & 63;
    const int qi = blockIdx.x * 4 + (tid >> 6);
    const int bh = qi >> 11;
    const int s = qi & (Sc - 1);
    const int b = bh / Hc, h = bh % Hc;
    float m0 = pm[qi], m1 = pm[NQ + qi], m2 = pm[2*NQ + qi], m3 = pm[3*NQ + qi];
    float M = fmaxf(fmaxf(m0, m1), fmaxf(m2, m3));
    float w0 = __expf(m0 - M), w1 = __expf(m1 - M);
    float w2 = __expf(m2 - M), w3 = __expf(m3 - M);
    float l = w0 * pl[qi] + w1 * pl[NQ + qi] + w2 * pl[2*NQ + qi] + w3 * pl[3*NQ + qi];
    float o = w0 * po[(size_t)qi * 64 + d]
            + w1 * po[((size_t)NQ + qi) * 64 + d]
            + w2 * po[((size_t)2*NQ + qi) * 64 + d]
            + w3 * po[((size_t)3*NQ + qi) * 64 + d];
    ao[((size_t)(b * Sc + s)) * Dm + h * 64 + d] = o / l;
}

// ---------------------------------------------------------------------------
__global__ __launch_bounds__(256) void conv_silu_kernel(
    const float* __restrict__ xz, const float* __restrict__ cw,
    const float* __restrict__ cb, float* __restrict__ u)
{
    int id = blockIdx.x * 256 + threadIdx.x;
    int d = id % DI;
    int r = id / DI;
    int s = r & (Sc - 1);
    int b = r >> 11;
    float acc = cb[d];
#pragma unroll
    for (int j = 0; j < 4; ++j) {
        int sp = s + j - 3;
        if (sp >= 0)
            acc += xz[((size_t)(b * Sc + sp)) * (2 * DI) + d] * cw[d * 4 + j];
    }
    u[id] = acc / (1.f + __expf(-acc));
}

// ---------------------------------------------------------------------------
__global__ __launch_bounds__(256) void scan_kernel(
    const float* __restrict__ delta, const float* __restrict__ u,
    const float* __restrict__ dbc, const float* __restrict__ A_log,
    const float* __restrict__ Dp, float* __restrict__ y)
{
    int gid = blockIdx.x * 256 + threadIdx.x;
    int n = gid & 15;
    int ch = gid >> 4;
    int b = ch / DI;
    int dd = ch - b * DI;
    float Av = -__expf(A_log[dd * NST + n]);
    float Dv = Dp[dd];
    const float* dp = delta + (size_t)b * Sc * DI + dd;
    const float* up = u     + (size_t)b * Sc * DI + dd;
    const float* Bp = dbc   + (size_t)b * Sc * 80 + DTR + n;
    const float* Cp = Bp + NST;
    float* yp = y + (size_t)b * Sc * DI + dd;
    float h = 0.f;
    constexpr int CH = 8;
    float cdt[CH], cu[CH], cB[CH], cC[CH];
    float ndt[CH], nu[CH], nB[CH], nC[CH];
#pragma unroll
    for (int i = 0; i < CH; ++i) {
        cdt[i] = dp[(size_t)i * DI]; cu[i] = up[(size_t)i * DI];
        cB[i] = Bp[(size_t)i * 80];  cC[i] = Cp[(size_t)i * 80];
    }
    for (int t0 = 0; t0 < Sc; t0 += CH) {
        bool more = (t0 + CH < Sc);
        if (more) {
#pragma unroll
            for (int i = 0; i < CH; ++i) {
                size_t t = t0 + CH + i;
                ndt[i] = dp[t * DI]; nu[i] = up[t * DI];
                nB[i] = Bp[t * 80];  nC[i] = Cp[t * 80];
            }
        }
#pragma unroll
        for (int i = 0; i < CH; ++i) {
            float dt = cdt[i];
            h = __expf(dt * Av) * h + dt * cu[i] * cB[i];
            float p = h * cC[i];
            p += __shfl_xor(p, 1, 16);
            p += __shfl_xor(p, 2, 16);
            p += __shfl_xor(p, 4, 16);
            p += __shfl_xor(p, 8, 16);
            if (n == 0) yp[(size_t)(t0 + i) * DI] = p + cu[i] * Dv;
        }
        if (more) {
#pragma unroll
            for (int i = 0; i < CH; ++i) {
                cdt[i] = ndt[i]; cu[i] = nu[i]; cB[i] = nB[i]; cC[i] = nC[i];
            }
        }
    }
}

// ---------------------------------------------------------------------------
__global__ __launch_bounds__(256) void ssmin_kernel(
    float* __restrict__ y, const float* __restrict__ xz)
{
    int id = blockIdx.x * 256 + threadIdx.x;
    int d = id % DI;
    int r = id / DI;
    float z = xz[(size_t)r * (2 * DI) + DI + d];
    y[id] = y[id] * (z / (1.f + __expf(-z)));
}

// ---------------------------------------------------------------------------
__global__ __launch_bounds__(256) void x1_kernel(
    const float* __restrict__ x, const float* __restrict__ g,
    const float* __restrict__ at, const float* __restrict__ sm,
    float* __restrict__ x1)
{
    int id = blockIdx.x * 256 + threadIdx.x;
    float gv = g[id];
    x1[id] = x[id] + gv * at[id] + (1.f - gv) * sm[id];
}

// ---------------------------------------------------------------------------
__global__ __launch_bounds__(256) void rowdot_kernel(
    const float* __restrict__ rh, const float* __restrict__ w2,
    const float* __restrict__ b2, float* __restrict__ sc)
{
    int lane = threadIdx.x & 63;
    int t = blockIdx.x * 4 + (threadIdx.x >> 6);
    const float* rp = rh + (size_t)t * 192;
    float sum = rp[lane] * w2[lane] + rp[lane + 64] * w2[lane + 64]
              + rp[lane + 128] * w2[lane + 128];
#pragma unroll
    for (int off = 32; off; off >>= 1) sum += __shfl_down(sum, off, 64);
    if (lane == 0) sc[t] = sum + b2[0];
}

// ---------------------------------------------------------------------------
__global__ __launch_bounds__(256) void topk_kernel(
    const float* __restrict__ sc, int* __restrict__ idxb)
{
    __shared__ float vals[Sc];
    __shared__ float rv[4];
    __shared__ int ri[4];
    const int b = blockIdx.x, tid = threadIdx.x;
    for (int i = tid; i < Sc; i += 256) vals[i] = sc[(size_t)b * Sc + i];
    __syncthreads();
    for (int it = 0; it < CAP; ++it) {
        float bv = -3.4e38f; int bi = 0x7fffffff;
        for (int i = tid; i < Sc; i += 256) {
            float v = vals[i];
            if (v > bv || (v == bv && i < bi)) { bv = v; bi = i; }
        }
#pragma unroll
        for (int off = 32; off; off >>= 1) {
            float ov = __shfl_down(bv, off, 64);
            int oi = __shfl_down(bi, off, 64);
            if (ov > bv || (ov == bv && oi < bi)) { bv = ov; bi = oi; }
        }
        int lane = tid & 63, wid = tid >> 6;
        if (lane == 0) { rv[wid] = bv; ri[wid] = bi; }
        __syncthreads();
        if (tid == 0) {
            float Bv = rv[0]; int Bi = ri[0];
            for (int w = 1; w < 4; ++w)
                if (rv[w] > Bv || (rv[w] == Bv && ri[w] < Bi)) { Bv = rv[w]; Bi = ri[w]; }
            idxb[b * CAP + it] = Bi;
            vals[Bi] = -3.4e38f;
        }
        __syncthreads();
    }
}

// ---------------------------------------------------------------------------
__global__ __launch_bounds__(256) void gather_kernel(
    const float* __restrict__ xn2, const int* __restrict__ idxb,
    float* __restrict__ Xsel)
{
    int i = blockIdx.x;
    int b = i >> 8;
    int t = idxb[i];
    const float* src = xn2 + ((size_t)(b * Sc + t)) * Dm;
    float* dst = Xsel + (size_t)i * Dm;
    int c = threadIdx.x;
    dst[c] = src[c]; dst[c + 256] = src[c + 256]; dst[c + 512] = src[c + 512];
}

__global__ __launch_bounds__(256) void finaladd_kernel(
    const float* __restrict__ x1, const float* __restrict__ xn2,
    float* __restrict__ out)
{
    int id = blockIdx.x * 256 + threadIdx.x;
    out[id] = x1[id] + xn2[id];
}

__global__ __launch_bounds__(256) void scatter_kernel(
    const float* __restrict__ x1, const float* __restrict__ proc,
    const int* __restrict__ idxb, float* __restrict__ out)
{
    int i = blockIdx.x;
    int b = i >> 8;
    int t = idxb[i];
    size_t ro = ((size_t)(b * Sc + t)) * Dm;
    const float* pp = proc + (size_t)i * Dm;
    int c = threadIdx.x;
    out[ro + c]       = x1[ro + c]       + pp[c];
    out[ro + c + 256] = x1[ro + c + 256] + pp[c + 256];
    out[ro + c + 512] = x1[ro + c + 512] + pp[c + 512];
}

// ---------------------------------------------------------------------------
extern "C" void kernel_launch(void* const* d_in, const int* in_sizes, int n_in,
                              void* d_out, int out_size, void* d_ws, size_t ws_size,
                              hipStream_t stream)
{
    (void)in_sizes; (void)n_in; (void)out_size; (void)ws_size;
    const float* x          = (const float*)d_in[0];
    const float* ln1_w      = (const float*)d_in[1];
    const float* ln1_b      = (const float*)d_in[2];
    const float* ln2_w      = (const float*)d_in[3];
    const float* ln2_b      = (const float*)d_in[4];
    const float* qkv_w      = (const float*)d_in[5];
    const float* attn_out_w = (const float*)d_in[6];
    const float* attn_out_b = (const float*)d_in[7];
    const float* in_proj_w  = (const float*)d_in[8];
    const float* conv_w     = (const float*)d_in[9];
    const float* conv_b     = (const float*)d_in[10];
    const float* x_proj_w   = (const float*)d_in[11];
    const float* dt_w       = (const float*)d_in[12];
    const float* dt_b       = (const float*)d_in[13];
    const float* A_log      = (const float*)d_in[14];
    const float* Dvec       = (const float*)d_in[15];
    const float* ssm_out_w  = (const float*)d_in[16];
    const float* gate_w     = (const float*)d_in[17];
    const float* gate_b     = (const float*)d_in[18];
    const float* ffn_w1     = (const float*)d_in[19];
    const float* ffn_b1     = (const float*)d_in[20];
    const float* ffn_w2     = (const float*)d_in[21];
    const float* ffn_b2     = (const float*)d_in[22];
    const float* r_w1       = (const float*)d_in[23];
    const float* r_b1       = (const float*)d_in[24];
    const float* r_w2       = (const float*)d_in[25];
    const float* r_b2       = (const float*)d_in[26];
    float* out = (float*)d_out;

    // ---- Layout (floats). End = 53,318,144 floats = 213.27 MB (< 215.24 proven).
    // FIX vs r8: idxb needs 512 ints = 512 FLOAT slots (2048 B); r8 reserved
    // only 128 -> idxb[128..511] aliased Xsel[0..383] -> garbage gather/scatter
    // indices -> device fault.
    float* ws  = (float*)d_ws;
    float* xn  = ws;                       // TOK           (live 1-6)
    float* ao  = ws + TOK;                 // TOK           (live 4.5-5)
    float* y   = ws;                       // 2*TOK         (live 10-12; xn/ao dead)
    float* qkv = ws + 2 * TOK;             // 9.44M         (live 2-4)
    float* xz  = ws + 2 * TOK;             // 12.58M        (live 6-11; over qkv)
    float* u   = ws + 18874368;            // 6.29M         (live 7-10)
    float* xn2 = ws + 18874368;            // TOK           (live 16+; u dead)
    float* dbc = ws + 25165824;            // 327,680       (live 8-10)
    float* attn_out = ws + 25493504;       // TOK           (live 5-15)
    float* ssm_out  = ws + 28639232;       // TOK           (live 12-15)
    float* g        = ws + 31784960;       // TOK           (live 13-15)
    float* x1       = ws + 34930688;       // TOK           (live 15+)
    float* po    = attn_out;               // 12.58M        (live 4-4.5; spans 4 slots)
    float* delta = ssm_out;                // 6.29M         (live 9-10; ssm_out+g slots)
    float* rh  = ws + 38076416;            // 786,432       (live 17-18)
    float* pmb = rh + 64;                  // 196,608 (guard gap vs po end)
    float* plb = pmb + (size_t)NCH * NQ;   // 196,608
    float* sc  = ws + 38862848;            // 4,096  -> ends 38,866,944
    int*   idxb = (int*)(ws + 38866944);   // 512 ints = 512 float slots
    float* Xsel = ws + 38867456;           // 393,216 -> ends 39,260,672
    float* Hsel = ws + 39260672;           // 1,572,864 -> ends 40,833,536
    float* proc = ws + 40833536;           // 393,216 -> ends 41,226,752
    short* wb   = (short*)(ws + 41226752); // 24,182,784 shorts (12,091,392 floats)
    short* qkvh = wb,            *qkvl = wb + 1769472;
    short* atth = wb + 3538944,  *attl = wb + 4128768;
    short* inph = wb + 4718592,  *inpl = wb + 7077888;
    short* xpjh = wb + 9437184,  *xpjl = wb + 9633792;
    short* dth  = wb + 9830400,  *dtl  = wb + 9928704;
    short* ssmh = wb + 10027008, *ssml = wb + 11206656;
    short* g1h  = wb + 12386304, *g1l  = wb + 12976128;
    short* g2h  = wb + 13565952, *g2l  = wb + 14155776;
    short* f1h  = wb + 14745600, *f1l  = wb + 17104896;
    short* f2h  = wb + 19464192, *f2l  = wb + 21823488;

    // ---- weight pre-swizzles (every launch)
    auto WS = [&](const float* W, short* Wh, short* Wl, int K, int N, int Kp, int Np) {
        int total = Kp * Np;
        wswz_kernel<<<(total + 255) / 256, 256, 0, stream>>>(W, Wh, Wl, K, N, Kp, Np);
    };
    WS(qkv_w, qkvh, qkvl, 768, 2304, 768, 2304);
    WS(attn_out_w, atth, attl, 768, 768, 768, 768);
    WS(in_proj_w, inph, inpl, 768, 3072, 768, 3072);
    WS(x_proj_w, xpjh, xpjl, 1536, 80, 1536, 128);
    WS(dt_w, dth, dtl, 48, 1536, 64, 1536);
    WS(ssm_out_w, ssmh, ssml, 1536, 768, 1536, 768);
    WS(gate_w, g1h, g1l, 768, 768, 768, 768);
    WS(gate_w + (size_t)768 * 768, g2h, g2l, 768, 768, 768, 768);
    WS(ffn_w1, f1h, f1l, 768, 3072, 768, 3072);
    WS(ffn_w2, f2h, f2l, 3072, 768, 3072, 768);

    // 1. LN1
    ln_kernel<<<M_, 256, 0, stream>>>(x, ln1_w, ln1_b, xn);
    // 2. QKV
    gemm_bf3<0><<<dim3(18, 32), 256, 0, stream>>>(xn, Dm, qkvh, qkvl, 144,
        nullptr, qkv, M_, 2304, 768, 0, 0);
    // 3. RoPE
    rope_kernel<<<(Bc * Sc * Hc * 32) / 256, 256, 0, stream>>>(qkv);
    // 4. attention
    attn_partial_kernel<<<dim3(Sc / 256, Bc * Hc, NCH), 256, 0, stream>>>(qkv, po, pmb, plb);
    attn_combine_kernel<<<NQ / 4, 256, 0, stream>>>(po, pmb, plb, ao);
    // 5. attn_out projection (po dead)
    gemm_bf3<1><<<dim3(6, 32), 256, 0, stream>>>(ao, Dm, atth, attl, 48,
        attn_out_b, attn_out, M_, 768, 768, 0, 0);
    // 6. in_proj (qkv dead; xz overwrites it)
    gemm_bf3<2><<<dim3(24, 32), 256, 0, stream>>>(xn, Dm, inph, inpl, 192,
        nullptr, xz, M_, 3072, 768, 0, 0);
    // 7. conv + SiLU
    conv_silu_kernel<<<(M_ * DI) / 256, 256, 0, stream>>>(xz, conv_w, conv_b, u);
    // 8. x_proj (N=80, Npad=128)
    gemm_bf3<3><<<dim3(1, 32), 256, 0, stream>>>(u, DI, xpjh, xpjl, 8,
        nullptr, dbc, M_, 80, 1536, 0, 0);
    // 9. delta = softplus(dbc[:,:48] @ dt_w + dt_b)  (K=48, Kpad=64 in B)
    gemm_bf3<4><<<dim3(12, 32), 256, 0, stream>>>(dbc, 80, dth, dtl, 96,
        dt_b, delta, M_, 1536, 48, 1, 0);
    // 10. scan -> y (xn/ao dead)
    scan_kernel<<<(Bc * DI * NST) / 256, 256, 0, stream>>>(delta, u, dbc, A_log, Dvec, y);
    // 11. y *= silu(z) in place (delta dead after scan)
    ssmin_kernel<<<(M_ * DI) / 256, 256, 0, stream>>>(y, xz);
    // 12. ssm_out
    gemm_bf3<5><<<dim3(6, 32), 256, 0, stream>>>(y, DI, ssmh, ssml, 48,
        nullptr, ssm_out, M_, 768, 1536, 0, 0);
    // 13/14. gate
    gemm_bf3<6><<<dim3(6, 32), 256, 0, stream>>>(attn_out, Dm, g1h, g1l, 48,
        nullptr, g, M_, 768, 768, 0, 0);
    gemm_bf3<7><<<dim3(6, 32), 256, 0, stream>>>(ssm_out, Dm, g2h, g2l, 48,
        gate_b, g, M_, 768, 768, 2, 1);
    // 15. x1
    x1_kernel<<<(M_ * Dm) / 256, 256, 0, stream>>>(x, g, attn_out, ssm_out, x1);
    // 16. LN2 (u dead -> xn2)
    ln_kernel<<<M_, 256, 0, stream>>>(x1, ln2_w, ln2_b, xn2);
    // 17. router (pure fp32, selection-critical)
    gemm_kernel<8><<<dim3(2, 32), 256, 0, stream>>>(xn2, Dm, r_w1, r_b1, rh, M_, 192, 768, 3, 0);
    // 18. scores
    rowdot_kernel<<<M_ / 4, 256, 0, stream>>>(rh, r_w2, r_b2, sc);
    // 19. top-k
    topk_kernel<<<Bc, 256, 0, stream>>>(sc, idxb);
    // 20. gather
    gather_kernel<<<Bc * CAP, 256, 0, stream>>>(xn2, idxb, Xsel);
    // 21. FFN1
    gemm_bf3<9><<<dim3(24, 4), 256, 0, stream>>>(Xsel, Dm, f1h, f1l, 192,
        ffn_b1, Hsel, Bc * CAP, DF, 768, 4, 0);
    // 22. FFN2
    gemm_bf3<10><<<dim3(6, 4), 256, 0, stream>>>(Hsel, DF, f2h, f2l, 48,
        ffn_b2, proc, Bc * CAP, 768, DF, 0, 0);
    // 23. out = x1 + xn2
    finaladd_kernel<<<(M_ * Dm) / 256, 256, 0, stream>>>(x1, xn2, out);
    // 24. scatter
    scatter_kernel<<<Bc * CAP, 256, 0, stream>>>(x1, proc, idxb, out);
}